// Round 12
// baseline (791.284 us; speedup 1.0000x reference)
//
#include <hip/hip_runtime.h>

#define TPB 256

typedef __attribute__((ext_vector_type(4))) float v4f;
typedef __attribute__((ext_vector_type(8))) short v8s;

__device__ __forceinline__ float us2f(unsigned int u) {
    union { unsigned int i; float f; } w; w.i = u << 16; return w.f;
}
__device__ __forceinline__ unsigned short f2us(float f) {
    union { float ff; unsigned int i; } w; w.ff = f;
    unsigned int u = w.i;
    return (unsigned short)((u + 0x7fffu + ((u >> 16) & 1u)) >> 16);
}
// Async global->LDS DMA, 16 B per lane. LDS dest = wave-uniform base + lane*16.
__device__ __forceinline__ void gl_lds16(const unsigned short* g, unsigned short* l) {
    __builtin_amdgcn_global_load_lds(
        (const __attribute__((address_space(1))) unsigned int*)g,
        (__attribute__((address_space(3))) unsigned int*)l, 16, 0, 0);
}

// ---------------------------------------------------------------------------
// Weight repacks (fp32 -> bf16, GEMM-friendly [tap][co][ci])
// ---------------------------------------------------------------------------
template<int CIN, int COUT, int KK>
__global__ __launch_bounds__(TPB) void repack_w(
    const float* __restrict__ w, unsigned short* __restrict__ o)
{
    int idx = blockIdx.x * TPB + threadIdx.x;
    if (idx >= KK * COUT * CIN) return;
    int ci = idx % CIN;
    int co = (idx / CIN) % COUT;
    int kk = idx / (CIN * COUT);
    o[idx] = f2us(w[((size_t)co * CIN + ci) * KK + kk]);
}
template<int CIN, int COUT>
__global__ __launch_bounds__(TPB) void repack_wt1(
    const float* __restrict__ w, unsigned short* __restrict__ o)
{
    int idx = blockIdx.x * TPB + threadIdx.x;
    if (idx >= CIN * COUT) return;
    int ci = idx % CIN;
    int co = idx / CIN;
    o[idx] = f2us(w[(size_t)ci * COUT + co]);
}
template<int CIN, int COUT>
__global__ __launch_bounds__(TPB) void repack_wct(
    const float* __restrict__ w, unsigned short* __restrict__ o)
{
    int idx = blockIdx.x * TPB + threadIdx.x;
    if (idx >= 16 * COUT * CIN) return;
    int ci = idx % CIN;
    int co = (idx / CIN) % COUT;
    int kidx = (idx / (CIN * COUT)) & 3;
    int cls = idx / (CIN * COUT * 4);
    int ohp = cls >> 1, owp = cls & 1;
    int kh = ((ohp + 1) & 1) + 2 * (kidx >> 1);
    int kw = ((owp + 1) & 1) + 2 * (kidx & 1);
    o[idx] = f2us(w[((size_t)ci * COUT + co) * 16 + kh * 4 + kw]);
}

// ---------------------------------------------------------------------------
// Encoder L1: direct conv 3->64, k3 s1 p1, NCHW fp32 x -> NHWC bf16.
// ---------------------------------------------------------------------------
__global__ __launch_bounds__(TPB) void conv_e1(
    const float* __restrict__ x, const float* __restrict__ w,
    const float* __restrict__ bias, unsigned short* __restrict__ y, int N)
{
    __shared__ float wl[27][64];
    int t = threadIdx.x;
    for (int i = t; i < 27 * 64; i += TPB) {
        int co = i & 63;
        int tap = i >> 6;
        int ci = tap / 9, kk = tap % 9;
        wl[tap][co] = w[((size_t)co * 3 + ci) * 9 + kk];
    }
    __syncthreads();
    int p = blockIdx.x * TPB + t;
    int n = p >> 12, oh = (p >> 6) & 63, ow = p & 63;
    float acc[64];
#pragma unroll
    for (int co = 0; co < 64; co++) acc[co] = bias[co];
    for (int ci = 0; ci < 3; ci++) {
#pragma unroll
        for (int kh = 0; kh < 3; kh++) {
            int ih = oh - 1 + kh;
            if ((unsigned)ih >= 64u) continue;
#pragma unroll
            for (int kw = 0; kw < 3; kw++) {
                int iw = ow - 1 + kw;
                if ((unsigned)iw >= 64u) continue;
                float xv = x[(((size_t)n * 3 + ci) * 64 + ih) * 64 + iw];
                int tap = ci * 9 + kh * 3 + kw;
#pragma unroll
                for (int co = 0; co < 64; co++) acc[co] += xv * wl[tap][co];
            }
        }
    }
    unsigned int* yp = (unsigned int*)(y + (size_t)p * 64);
#pragma unroll
    for (int co = 0; co < 64; co += 2)
        yp[co >> 1] = (unsigned int)f2us(acc[co]) | ((unsigned int)f2us(acc[co + 1]) << 16);
}

// ---------------------------------------------------------------------------
// MFMA implicit-GEMM conv, DMA-staged, BK=64, fused BN-stat partials.
// NYB==2: XCD-aware decode (b, b+8 share an XCD under round-robin dispatch).
// OUTM: 0 = bf16 out + BN partials; 2 = split hi/lo bf16 out (no BN).
// ---------------------------------------------------------------------------
template<int CIN, int COUT, int HIN, int WIN, int K, int S, int P, int BN,
         int OUTM, int NYB>
__global__ __launch_bounds__(TPB) void conv_mfma(
    const unsigned short* __restrict__ xin, const unsigned short* __restrict__ wrep,
    const float* __restrict__ bias, void* __restrict__ yout, void* __restrict__ yout2,
    float* __restrict__ part, const unsigned short* __restrict__ zpage, int N)
{
    constexpr int HOUT = (HIN + 2 * P - K) / S + 1;
    constexpr int WOUT = (WIN + 2 * P - K) / S + 1;
    constexpr int RN = BN / 32;
    constexpr int BSEG = BN / 16;
    __shared__ __align__(16) unsigned short Ab[16 * 512];
    __shared__ __align__(16) unsigned short Bb[2 * BSEG * 512];

    const int t = threadIdx.x, lane = t & 63, wave = t >> 6;
    const int wm = wave >> 1, wn = wave & 1;
    int m0, co0;
    if (NYB == 2) {
        int g = (int)blockIdx.x >> 3, xs = (int)blockIdx.x & 7;
        co0 = (g & 1) * BN;
        m0 = (((g >> 1) << 3) + xs) * 128;
    } else {
        m0 = (int)blockIdx.x * 128;
        co0 = 0;
    }
    const int lr = lane & 15, lc = lane >> 4;

    int n_[2], oh_[2], ow_[2];
#pragma unroll
    for (int i = 0; i < 2; i++) {
        int r = m0 + (wave + 4 * i) * 16 + lr;
        n_[i] = r / (HOUT * WOUT);
        int rem = r % (HOUT * WOUT);
        oh_[i] = rem / WOUT;
        ow_[i] = rem % WOUT;
    }

    v4f acc[4][RN];
#pragma unroll
    for (int i = 0; i < 4; i++)
#pragma unroll
        for (int j = 0; j < RN; j++)
#pragma unroll
            for (int r = 0; r < 4; r++) acc[i][j][r] = 0.f;

    for (int kk = 0; kk < K * K; kk++) {
        const int kh = kk / K, kw = kk % K;
        const unsigned short* ga[2];
#pragma unroll
        for (int i = 0; i < 2; i++) {
            int ih = oh_[i] * S - P + kh;
            int iw = ow_[i] * S - P + kw;
            bool av = (unsigned)ih < (unsigned)HIN && (unsigned)iw < (unsigned)WIN;
            ga[i] = av ? xin + (((size_t)n_[i] * HIN + ih) * WIN + iw) * CIN + lc * 8
                       : (const unsigned short*)nullptr;
        }
        const unsigned short* wt = wrep + (size_t)kk * COUT * CIN;
        for (int ci0 = 0; ci0 < CIN; ci0 += 64) {
            __syncthreads();
#pragma unroll
            for (int i = 0; i < 2; i++) {
                const unsigned short* b0 = ga[i] ? ga[i] + ci0 : zpage;
                const unsigned short* b1 = ga[i] ? ga[i] + ci0 + 32 : zpage;
                gl_lds16(b0, &Ab[(wave + 4 * i) * 512]);
                gl_lds16(b1, &Ab[(8 + wave + 4 * i) * 512]);
            }
#pragma unroll
            for (int i = 0; i < 2; i++) {
                int sgb = wave + 4 * i;
                if (sgb < BSEG) {
                    const unsigned short* wb =
                        wt + (size_t)(co0 + sgb * 16 + lr) * CIN + ci0 + lc * 8;
                    gl_lds16(wb, &Bb[sgb * 512]);
                    gl_lds16(wb + 32, &Bb[(BSEG + sgb) * 512]);
                }
            }
            __syncthreads();

#pragma unroll
            for (int kc = 0; kc < 2; kc++) {
                v8s a[4], b[RN];
#pragma unroll
                for (int i = 0; i < 4; i++)
                    a[i] = *(const v8s*)&Ab[(kc * 8 + wm * 4 + i) * 512 + lane * 8];
#pragma unroll
                for (int j = 0; j < RN; j++)
                    b[j] = *(const v8s*)&Bb[(kc * BSEG + wn * RN + j) * 512 + lane * 8];
#pragma unroll
                for (int i = 0; i < 4; i++)
#pragma unroll
                    for (int j = 0; j < RN; j++)
                        acc[i][j] = __builtin_amdgcn_mfma_f32_16x16x32_bf16(a[i], b[j], acc[i][j], 0, 0, 0);
            }
        }
    }

    float sloc[RN], qloc[RN];
#pragma unroll
    for (int j = 0; j < RN; j++) { sloc[j] = 0.f; qloc[j] = 0.f; }

#pragma unroll
    for (int i = 0; i < 4; i++) {
        int mr = wm * 64 + i * 16 + (lane >> 4) * 4;
#pragma unroll
        for (int j = 0; j < RN; j++) {
            int col = co0 + wn * (BN / 2) + j * 16 + (lane & 15);
            float bs = bias[col];
#pragma unroll
            for (int r = 0; r < 4; r++) {
                size_t g = (size_t)(m0 + mr + r) * COUT + col;
                float v = acc[i][j][r] + bs;
                if (OUTM == 2) {
                    unsigned short h = f2us(v);
                    ((unsigned short*)yout)[g] = h;
                    ((unsigned short*)yout2)[g] = f2us(v - us2f(h));
                } else {
                    ((unsigned short*)yout)[g] = f2us(v);
                    sloc[j] += v;
                    qloc[j] += v * v;
                }
            }
        }
    }

    if (OUTM == 0) {
        __syncthreads();
        float* red = (float*)Ab;
        for (int i = t; i < 2 * BN; i += TPB) red[i] = 0.f;
        __syncthreads();
#pragma unroll
        for (int j = 0; j < RN; j++) {
            float s = sloc[j], qv = qloc[j];
            s += __shfl_xor(s, 16); s += __shfl_xor(s, 32);
            qv += __shfl_xor(qv, 16); qv += __shfl_xor(qv, 32);
            if ((lane >> 4) == 0) {
                int cl = wn * (BN / 2) + j * 16 + (lane & 15);
                atomicAdd(&red[cl], s);
                atomicAdd(&red[BN + cl], qv);
            }
        }
        __syncthreads();
        int pb = (NYB == 2) ? (m0 >> 7) : (int)blockIdx.x;
        int PB = (NYB == 2) ? ((int)gridDim.x >> 1) : (int)gridDim.x;
        for (int i = t; i < BN; i += TPB) {
            int col = co0 + i;
            part[(size_t)col * PB + pb] = red[i];
            part[(size_t)(COUT + col) * PB + pb] = red[BN + i];
        }
    }
}

// ---------------------------------------------------------------------------
// MFMA implicit-GEMM transposed conv, k4 s2 p1, BK=64, XCD-aware classes.
// OUTPUT IS CLASS-MAJOR: (cls, n, i, j, co) — epilogue is a LINEAR store
// (row*COUT+col), no oh/ow decompose, coalesced. Consumers remap with shifts.
// IN_CLS: input tensor is itself class-major (produced by a previous convt).
// ---------------------------------------------------------------------------
template<int CIN, int COUT, int HIN, int WIN, int BN, int IN_CLS>
__global__ __launch_bounds__(TPB) void convt_mfma(
    const unsigned short* __restrict__ xin, const unsigned short* __restrict__ wrep,
    const float* __restrict__ bias, unsigned short* __restrict__ yout,
    float* __restrict__ part, const unsigned short* __restrict__ zpage, int N)
{
    constexpr int RN = BN / 32;
    constexpr int BSEG = BN / 16;
    __shared__ __align__(16) unsigned short Ab[16 * 512];
    __shared__ __align__(16) unsigned short Bb[2 * BSEG * 512];

    const int t = threadIdx.x, lane = t & 63, wave = t >> 6;
    const int wm = wave >> 1, wn = wave & 1;
    const int gdec = (int)blockIdx.x >> 3, xs = (int)blockIdx.x & 7;
    const int cls = gdec & 3;
    const int m0 = (((gdec >> 2) << 3) + xs) * 128;
    const int ohp = cls >> 1, owp = cls & 1;
    const int khb = (ohp + 1) & 1, kwb = (owp + 1) & 1;
    const int dh0 = (ohp + 1 - khb) >> 1, dw0 = (owp + 1 - kwb) >> 1;
    const int lr = lane & 15, lc = lane >> 4;

    int n_[2], i_[2], j_[2];
#pragma unroll
    for (int i = 0; i < 2; i++) {
        int r = m0 + (wave + 4 * i) * 16 + lr;
        n_[i] = r / (HIN * WIN);
        int rem = r % (HIN * WIN);
        i_[i] = rem / WIN;
        j_[i] = rem % WIN;
    }

    v4f acc[4][RN];
#pragma unroll
    for (int i = 0; i < 4; i++)
#pragma unroll
        for (int j = 0; j < RN; j++)
#pragma unroll
            for (int r = 0; r < 4; r++) acc[i][j][r] = 0.f;

    for (int kidx = 0; kidx < 4; kidx++) {
        const int dh = dh0 - (kidx >> 1);
        const int dw = dw0 - (kidx & 1);
        const unsigned short* ga[2];
#pragma unroll
        for (int i = 0; i < 2; i++) {
            int ih = i_[i] + dh;
            int iw = j_[i] + dw;
            bool av = (unsigned)ih < (unsigned)HIN && (unsigned)iw < (unsigned)WIN;
            size_t abase;
            if (IN_CLS) {
                int clsi = ((ih & 1) << 1) | (iw & 1);
                abase = ((((size_t)clsi * N + n_[i]) * (HIN / 2) + (ih >> 1)) * (WIN / 2)
                         + (iw >> 1)) * CIN;
            } else {
                abase = (((size_t)n_[i] * HIN + ih) * WIN + iw) * CIN;
            }
            ga[i] = av ? xin + abase + lc * 8 : (const unsigned short*)nullptr;
        }
        const unsigned short* wk = wrep + (size_t)(cls * 4 + kidx) * COUT * CIN;
        for (int ci0 = 0; ci0 < CIN; ci0 += 64) {
            __syncthreads();
#pragma unroll
            for (int i = 0; i < 2; i++) {
                const unsigned short* b0 = ga[i] ? ga[i] + ci0 : zpage;
                const unsigned short* b1 = ga[i] ? ga[i] + ci0 + 32 : zpage;
                gl_lds16(b0, &Ab[(wave + 4 * i) * 512]);
                gl_lds16(b1, &Ab[(8 + wave + 4 * i) * 512]);
            }
#pragma unroll
            for (int i = 0; i < 2; i++) {
                int sgb = wave + 4 * i;
                if (sgb < BSEG) {
                    const unsigned short* wb =
                        wk + (size_t)(sgb * 16 + lr) * CIN + ci0 + lc * 8;
                    gl_lds16(wb, &Bb[sgb * 512]);
                    gl_lds16(wb + 32, &Bb[(BSEG + sgb) * 512]);
                }
            }
            __syncthreads();

#pragma unroll
            for (int kc = 0; kc < 2; kc++) {
                v8s a[4], b[RN];
#pragma unroll
                for (int i = 0; i < 4; i++)
                    a[i] = *(const v8s*)&Ab[(kc * 8 + wm * 4 + i) * 512 + lane * 8];
#pragma unroll
                for (int j = 0; j < RN; j++)
                    b[j] = *(const v8s*)&Bb[(kc * BSEG + wn * RN + j) * 512 + lane * 8];
#pragma unroll
                for (int i = 0; i < 4; i++)
#pragma unroll
                    for (int j = 0; j < RN; j++)
                        acc[i][j] = __builtin_amdgcn_mfma_f32_16x16x32_bf16(a[i], b[j], acc[i][j], 0, 0, 0);
            }
        }
    }

    float sloc[RN], qloc[RN];
#pragma unroll
    for (int j = 0; j < RN; j++) { sloc[j] = 0.f; qloc[j] = 0.f; }

    const size_t clsbase = (size_t)cls * N * HIN * WIN;   // class-major rows
#pragma unroll
    for (int i = 0; i < 4; i++) {
        int mr = wm * 64 + i * 16 + (lane >> 4) * 4;
#pragma unroll
        for (int j = 0; j < RN; j++) {
            int col = wn * (BN / 2) + j * 16 + (lane & 15);
            float bs = bias[col];
#pragma unroll
            for (int r = 0; r < 4; r++) {
                size_t gi = (clsbase + m0 + mr + r) * COUT + col;
                float v = acc[i][j][r] + bs;
                yout[gi] = f2us(v);
                sloc[j] += v;
                qloc[j] += v * v;
            }
        }
    }

    __syncthreads();
    float* red = (float*)Ab;
    for (int i = t; i < 2 * BN; i += TPB) red[i] = 0.f;
    __syncthreads();
#pragma unroll
    for (int j = 0; j < RN; j++) {
        float s = sloc[j], qv = qloc[j];
        s += __shfl_xor(s, 16); s += __shfl_xor(s, 32);
        qv += __shfl_xor(qv, 16); qv += __shfl_xor(qv, 32);
        if ((lane >> 4) == 0) {
            int cl = wn * (BN / 2) + j * 16 + (lane & 15);
            atomicAdd(&red[cl], s);
            atomicAdd(&red[BN + cl], qv);
        }
    }
    __syncthreads();
    int pb = (int)blockIdx.x;
    int PB = (int)gridDim.x;
    for (int i = t; i < BN; i += TPB) {
        part[(size_t)i * PB + pb] = red[i];
        part[(size_t)(COUT + i) * PB + pb] = red[BN + i];
    }
}

// ---------------------------------------------------------------------------
// BN stats pass (only for h1 / conv_e1 output), transposed partial store.
// ---------------------------------------------------------------------------
template<int C>
__global__ __launch_bounds__(TPB) void bn_stats_p(
    const unsigned short* __restrict__ x, float* __restrict__ part, int M)
{
    constexpr int GPT = C / 8;
    constexpr int RPB = TPB / GPT;
    constexpr int ACT = RPB * GPT;
    __shared__ float sred[2 * C];
    int t = threadIdx.x;
    for (int i = t; i < 2 * C; i += TPB) sred[i] = 0.f;
    __syncthreads();
    if (t < ACT) {
        int g = t % GPT, rs = t / GPT;
        float s[8], sq[8];
#pragma unroll
        for (int k = 0; k < 8; k++) { s[k] = 0.f; sq[k] = 0.f; }
        for (int row = blockIdx.x * RPB + rs; row < M; row += gridDim.x * RPB) {
            int4 v = *(const int4*)(x + (size_t)row * C + g * 8);
            const unsigned int* vu = (const unsigned int*)&v;
#pragma unroll
            for (int k = 0; k < 4; k++) {
                float f0 = us2f(vu[k] & 0xffffu);
                float f1 = us2f(vu[k] >> 16);
                s[2 * k] += f0; sq[2 * k] += f0 * f0;
                s[2 * k + 1] += f1; sq[2 * k + 1] += f1 * f1;
            }
        }
        int c0 = g * 8;
#pragma unroll
        for (int k = 0; k < 8; k++) {
            atomicAdd(&sred[c0 + k], s[k]);
            atomicAdd(&sred[C + c0 + k], sq[k]);
        }
    }
    __syncthreads();
    int B = gridDim.x;
    for (int i = t; i < 2 * C; i += TPB)
        part[(size_t)i * B + blockIdx.x] = sred[i];
}

template<int C>
__global__ __launch_bounds__(64) void bn_reduce2(
    const float* __restrict__ part, float* __restrict__ st, int B)
{
    int i = blockIdx.x;
    int lane = threadIdx.x;
    float s = 0.f;
    for (int b = lane; b < B; b += 64) s += part[(size_t)i * B + b];
#pragma unroll
    for (int off = 1; off < 64; off <<= 1) s += __shfl_xor(s, off);
    if (lane == 0) st[i] = s;
}

template<int C>
__global__ __launch_bounds__(TPB) void bn_apply_v(
    unsigned short* __restrict__ x, const float* __restrict__ st,
    const float* __restrict__ g, const float* __restrict__ be, int M)
{
    __shared__ float sc[C], sh[C];
    int t = threadIdx.x;
    float cnt = (float)M;
    for (int c = t; c < C; c += TPB) {
        float m = st[c] / cnt;
        float v = st[C + c] / cnt - m * m;
        float s = g[c] * rsqrtf(v + 1e-5f);
        sc[c] = s;
        sh[c] = be[c] - m * s;
    }
    __syncthreads();
    constexpr int GPT = C / 8;
    size_t tot = (size_t)M * GPT;
    for (size_t slot = (size_t)blockIdx.x * TPB + t; slot < tot;
         slot += (size_t)gridDim.x * TPB) {
        int c0 = (int)(slot % GPT) * 8;
        int4 v = *(int4*)(x + slot * 8);
        unsigned int* vu = (unsigned int*)&v;
#pragma unroll
        for (int k = 0; k < 4; k++) {
            float f0 = fmaxf(us2f(vu[k] & 0xffffu) * sc[c0 + 2 * k] + sh[c0 + 2 * k], 0.f);
            float f1 = fmaxf(us2f(vu[k] >> 16) * sc[c0 + 2 * k + 1] + sh[c0 + 2 * k + 1], 0.f);
            vu[k] = (unsigned int)f2us(f0) | ((unsigned int)f2us(f1) << 16);
        }
        *(int4*)(x + slot * 8) = v;
    }
}

// ---------------------------------------------------------------------------
// VQ stage 1: codebook split hi/lo bf16 + cn2.
// ---------------------------------------------------------------------------
__global__ __launch_bounds__(TPB) void cb_prep(
    const float* __restrict__ cb, unsigned short* __restrict__ chb,
    unsigned short* __restrict__ clb, float* __restrict__ cn2)
{
    int j = blockIdx.x, d = threadIdx.x;
    float v = cb[j * 256 + d];
    unsigned short h = f2us(v);
    chb[j * 256 + d] = h;
    clb[j * 256 + d] = f2us(v - us2f(h));
    float s = v * v;
#pragma unroll
    for (int off = 1; off < 64; off <<= 1) s += __shfl_xor(s, off);
    __shared__ float p[4];
    if ((d & 63) == 0) p[d >> 6] = s;
    __syncthreads();
    if (d == 0) cn2[j] = p[0] + p[1] + p[2] + p[3];
}

// ---------------------------------------------------------------------------
// VQ stage 2: split-bf16 MFMA distance GEMM with fused per-wave argmin.
// Each wave owns 64 cols -> candidate slot row*4 + cbk*2 + wn (race-free).
// ---------------------------------------------------------------------------
__global__ __launch_bounds__(TPB) void vq_gemm(
    const unsigned short* __restrict__ zh, const unsigned short* __restrict__ zl,
    const unsigned short* __restrict__ chb, const unsigned short* __restrict__ clb,
    const float* __restrict__ cn2, float* __restrict__ valp, int* __restrict__ idxp)
{
    __shared__ __align__(16) unsigned short Ah[8 * 512];
    __shared__ __align__(16) unsigned short Al[8 * 512];
    __shared__ __align__(16) unsigned short Bh[8 * 512];
    __shared__ __align__(16) unsigned short Bl[8 * 512];

    const int t = threadIdx.x, lane = t & 63, wave = t >> 6;
    const int wm = wave >> 1, wn = wave & 1;
    const int gdec = (int)blockIdx.x >> 3, xs = (int)blockIdx.x & 7;
    const int cbk = gdec & 1;
    const int m0 = (((gdec >> 1) << 3) + xs) * 128;
    const int co0 = cbk * 128;
    const int lr = lane & 15, lc = lane >> 4;

    size_t a0 = (size_t)(m0 + wave * 16 + lr) * 256 + lc * 8;
    size_t a1 = a0 + 64 * 256;
    size_t b0 = (size_t)(co0 + wave * 16 + lr) * 256 + lc * 8;
    size_t b1 = b0 + 64 * 256;

    v4f acc[4][4];
#pragma unroll
    for (int i = 0; i < 4; i++)
#pragma unroll
        for (int j = 0; j < 4; j++)
#pragma unroll
            for (int r = 0; r < 4; r++) acc[i][j][r] = 0.f;

    for (int ci0 = 0; ci0 < 256; ci0 += 32) {
        __syncthreads();
        gl_lds16(zh + a0 + ci0, &Ah[wave * 512]);
        gl_lds16(zh + a1 + ci0, &Ah[(wave + 4) * 512]);
        gl_lds16(zl + a0 + ci0, &Al[wave * 512]);
        gl_lds16(zl + a1 + ci0, &Al[(wave + 4) * 512]);
        gl_lds16(chb + b0 + ci0, &Bh[wave * 512]);
        gl_lds16(chb + b1 + ci0, &Bh[(wave + 4) * 512]);
        gl_lds16(clb + b0 + ci0, &Bl[wave * 512]);
        gl_lds16(clb + b1 + ci0, &Bl[(wave + 4) * 512]);
        __syncthreads();

        v8s a_h[4], a_l[4], b_h[4], b_l[4];
#pragma unroll
        for (int i = 0; i < 4; i++) {
            a_h[i] = *(const v8s*)&Ah[(wm * 4 + i) * 512 + lane * 8];
            a_l[i] = *(const v8s*)&Al[(wm * 4 + i) * 512 + lane * 8];
        }
#pragma unroll
        for (int j = 0; j < 4; j++) {
            b_h[j] = *(const v8s*)&Bh[(wn * 4 + j) * 512 + lane * 8];
            b_l[j] = *(const v8s*)&Bl[(wn * 4 + j) * 512 + lane * 8];
        }
#pragma unroll
        for (int i = 0; i < 4; i++)
#pragma unroll
            for (int j = 0; j < 4; j++) {
                acc[i][j] = __builtin_amdgcn_mfma_f32_16x16x32_bf16(a_h[i], b_h[j], acc[i][j], 0, 0, 0);
                acc[i][j] = __builtin_amdgcn_mfma_f32_16x16x32_bf16(a_h[i], b_l[j], acc[i][j], 0, 0, 0);
                acc[i][j] = __builtin_amdgcn_mfma_f32_16x16x32_bf16(a_l[i], b_h[j], acc[i][j], 0, 0, 0);
            }
    }

#pragma unroll
    for (int i = 0; i < 4; i++) {
#pragma unroll
        for (int r = 0; r < 4; r++) {
            float best = 3.4e38f;
            int bi = 0;
#pragma unroll
            for (int j = 0; j < 4; j++) {
                int col = co0 + wn * 64 + j * 16 + (lane & 15);
                float d = cn2[col] - 2.f * acc[i][j][r];
                if (d < best || (d == best && col < bi)) { best = d; bi = col; }
            }
#pragma unroll
            for (int off = 1; off < 16; off <<= 1) {
                float ov = __shfl_xor(best, off);
                int oi = __shfl_xor(bi, off);
                if (ov < best || (ov == best && oi < bi)) { best = ov; bi = oi; }
            }
            if ((lane & 15) == 0) {
                int row = m0 + wm * 64 + i * 16 + (lane >> 4) * 4 + r;
                valp[(size_t)row * 4 + cbk * 2 + wn] = best;
                idxp[(size_t)row * 4 + cbk * 2 + wn] = bi;
            }
        }
    }
}

// ---------------------------------------------------------------------------
// VQ stage 3+4 fused: per-row candidate combine (strict < keeps smallest
// index on ties; slots ordered by ascending column range) + gather + loss.
// ---------------------------------------------------------------------------
__global__ __launch_bounds__(TPB) void vq_gather2(
    const unsigned short* __restrict__ zh, const unsigned short* __restrict__ zl,
    const float* __restrict__ cb, const float* __restrict__ valp,
    const int* __restrict__ idxp, unsigned short* __restrict__ hq,
    float* __restrict__ rowloss)
{
    int row = blockIdx.x * 4 + (threadIdx.x >> 6);
    int lane = threadIdx.x & 63;
    float best = valp[(size_t)row * 4];
    int j = idxp[(size_t)row * 4];
#pragma unroll
    for (int c = 1; c < 4; c++) {
        float v = valp[(size_t)row * 4 + c];
        if (v < best) { best = v; j = idxp[(size_t)row * 4 + c]; }
    }
    ushort4 hv = *(const ushort4*)(zh + (size_t)row * 256 + lane * 4);
    ushort4 lv = *(const ushort4*)(zl + (size_t)row * 256 + lane * 4);
    float4 cv = *(const float4*)(cb + (size_t)j * 256 + lane * 4);
    float z0 = us2f(hv.x) + us2f(lv.x);
    float z1 = us2f(hv.y) + us2f(lv.y);
    float z2 = us2f(hv.z) + us2f(lv.z);
    float z3 = us2f(hv.w) + us2f(lv.w);
    float d0 = z0 - cv.x, d1 = z1 - cv.y, d2 = z2 - cv.z, d3 = z3 - cv.w;
    float d = d0 * d0 + d1 * d1 + d2 * d2 + d3 * d3;
#pragma unroll
    for (int off = 1; off < 64; off <<= 1) d += __shfl_xor(d, off);
    if (lane == 0) rowloss[row] = d;
    ushort4 o;
    o.x = f2us(cv.x); o.y = f2us(cv.y); o.z = f2us(cv.z); o.w = f2us(cv.w);
    *(ushort4*)(hq + (size_t)row * 256 + lane * 4) = o;
}

__global__ __launch_bounds__(TPB) void loss_reduce1(
    const float* __restrict__ rowloss, float* __restrict__ part64)
{
    int t = threadIdx.x;
    int base = blockIdx.x * 512 + t;
    float v = rowloss[base] + rowloss[base + 256];
#pragma unroll
    for (int off = 1; off < 64; off <<= 1) v += __shfl_xor(v, off);
    __shared__ float p[4];
    if ((t & 63) == 0) p[t >> 6] = v;
    __syncthreads();
    if (t == 0) part64[blockIdx.x] = p[0] + p[1] + p[2] + p[3];
}

__global__ __launch_bounds__(64) void loss_finalize(
    const float* __restrict__ part64, float* __restrict__ out2)
{
    float v = part64[threadIdx.x];
    for (int off = 32; off > 0; off >>= 1) v += __shfl_down(v, off);
    if (threadIdx.x == 0) {
        float m = v * (1.0f / 32768.0f);
        out2[0] = m;
        out2[1] = m;
    }
}

// ---------------------------------------------------------------------------
// Decoder L4: direct conv 64->3, k3 s1 p1; input g3 is CLASS-MAJOR
// (cls, n, i, j, co) from D3 — remap with shifts. Output NCHW fp32 d_out.
// ---------------------------------------------------------------------------
__global__ __launch_bounds__(TPB) void conv_d4(
    const unsigned short* __restrict__ xb, const float* __restrict__ w,
    const float* __restrict__ bias, float* __restrict__ out, int N)
{
    __shared__ float wl[1728];
    int t = threadIdx.x;
    for (int i = t; i < 1728; i += TPB) {
        int co = i % 3, ci = (i / 3) % 64, tap = i / 192;
        wl[i] = w[((size_t)co * 64 + ci) * 9 + tap];
    }
    __syncthreads();
    int p = blockIdx.x * TPB + t;
    int n = p >> 12, oh = (p >> 6) & 63, ow = p & 63;
    float a0 = bias[0], a1 = bias[1], a2 = bias[2];
#pragma unroll
    for (int kh = 0; kh < 3; kh++) {
        int ih = oh - 1 + kh;
        if ((unsigned)ih >= 64u) continue;
#pragma unroll
        for (int kw = 0; kw < 3; kw++) {
            int iw = ow - 1 + kw;
            if ((unsigned)iw >= 64u) continue;
            int clsi = ((ih & 1) << 1) | (iw & 1);
            size_t row = (((size_t)clsi * 128 + n) * 32 + (ih >> 1)) * 32 + (iw >> 1);
            const unsigned short* xp = xb + row * 64;
            int tap = kh * 3 + kw;
#pragma unroll
            for (int c8 = 0; c8 < 8; c8++) {
                int4 v = *(const int4*)(xp + c8 * 8);
                const unsigned int* vu = (const unsigned int*)&v;
#pragma unroll
                for (int k = 0; k < 4; k++) {
                    unsigned int u = vu[k];
                    float f0 = us2f(u & 0xffffu);
                    float f1 = us2f(u >> 16);
                    const float* wp = &wl[(tap * 64 + c8 * 8 + k * 2) * 3];
                    a0 += f0 * wp[0]; a1 += f0 * wp[1]; a2 += f0 * wp[2];
                    a0 += f1 * wp[3]; a1 += f1 * wp[4]; a2 += f1 * wp[5];
                }
            }
        }
    }
    size_t base = (size_t)n * 3 * 4096 + oh * 64 + ow;
    out[base] = a0;
    out[base + 4096] = a1;
    out[base + 8192] = a2;
}

// ---------------------------------------------------------------------------

extern "C" void kernel_launch(void* const* d_in, const int* in_sizes, int n_in,
                              void* d_out, int out_size, void* d_ws, size_t ws_size,
                              hipStream_t stream) {
    const float* x    = (const float*)d_in[0];
    const float* cb   = (const float*)d_in[1];
    const float* e_w1 = (const float*)d_in[2];  const float* e_b1 = (const float*)d_in[3];
    const float* e_g1 = (const float*)d_in[4];  const float* e_be1 = (const float*)d_in[5];
    const float* e_w2 = (const float*)d_in[6];  const float* e_b2 = (const float*)d_in[7];
    const float* e_g2 = (const float*)d_in[8];  const float* e_be2 = (const float*)d_in[9];
    const float* e_w3 = (const float*)d_in[10]; const float* e_b3 = (const float*)d_in[11];
    const float* e_g3 = (const float*)d_in[12]; const float* e_be3 = (const float*)d_in[13];
    const float* e_w4 = (const float*)d_in[14]; const float* e_b4 = (const float*)d_in[15];
    const float* d_w1 = (const float*)d_in[16]; const float* d_b1 = (const float*)d_in[17];
    const float* d_g1 = (const float*)d_in[18]; const float* d_be1 = (const float*)d_in[19];
    const float* d_w2 = (const float*)d_in[20]; const float* d_b2 = (const float*)d_in[21];
    const float* d_g2 = (const float*)d_in[22]; const float* d_be2 = (const float*)d_in[23];
    const float* d_w3 = (const float*)d_in[24]; const float* d_b3 = (const float*)d_in[25];
    const float* d_g3 = (const float*)d_in[26]; const float* d_be3 = (const float*)d_in[27];
    const float* d_w4 = (const float*)d_in[28]; const float* d_b4 = (const float*)d_in[29];

    float* ws = (float*)d_ws;
    unsigned short* h1 = (unsigned short*)(ws);              // [0, 16777216)
    unsigned short* g3 = h1;                                 // class-major after D3
    unsigned short* h2 = (unsigned short*)(ws + 16777216);   // [.., 25165824)
    unsigned short* g2 = h2;                                 // class-major after D2
    unsigned short* h3 = (unsigned short*)(ws + 25165824);   // [.., 28311552)
    unsigned short* g1 = h3;
    unsigned short* zh = (unsigned short*)(ws + 28311552);   // 8.4M shorts
    unsigned short* zl = (unsigned short*)(ws + 32505856);   // 8.4M shorts
    unsigned short* hq = (unsigned short*)(ws + 36700160);   // [.., 40894464)
    float* stats = ws + 40960000;                            // 3072
    float* cn2 = ws + 40995904;                              // 256
    unsigned short* chb = (unsigned short*)(ws + 40996160);  // 65536 shorts
    unsigned short* clb = (unsigned short*)(ws + 41028928);  // 65536 shorts
    unsigned short* wrep = (unsigned short*)(ws + 41061696);
    unsigned short* we2 = wrep + 0;        // 16*128*64   = 131072
    unsigned short* we3 = wrep + 131072;   // 16*192*128  = 393216
    unsigned short* we4 = wrep + 524288;   // 256*192     = 49152
    unsigned short* wd1 = wrep + 573440;   // 192*256     = 49152
    unsigned short* wd2 = wrep + 622592;   // 4*4*128*192 = 393216
    unsigned short* wd3 = wrep + 1015808;  // 4*4*64*128  = 131072
    float* part = ws + 41635136;           // BN partials / VQ candidates (8.4M floats)
    float* valp = part;                    // 131072 floats (dead outside VQ window)
    int* idxp = (int*)(part + 131072);     // 131072 ints
    float* rowloss = ws + 50023744;                          // 32768
    float* part64 = ws + 50122048;                           // 64
    unsigned short* zpage = (unsigned short*)(ws + 50122112); // 256 B of zeros
    float* out = (float*)d_out;
    float* losses = out + 1572864;

    const int N = 128;

    hipMemsetAsync(zpage, 0, 256, stream);

    // weight / codebook prep (tiny)
    repack_w<64, 128, 16><<<512, TPB, 0, stream>>>(e_w2, we2);
    repack_w<128, 192, 16><<<1536, TPB, 0, stream>>>(e_w3, we3);
    repack_w<192, 256, 1><<<192, TPB, 0, stream>>>(e_w4, we4);
    repack_wt1<256, 192><<<192, TPB, 0, stream>>>(d_w1, wd1);
    repack_wct<192, 128><<<1536, TPB, 0, stream>>>(d_w2, wd2);
    repack_wct<128, 64><<<512, TPB, 0, stream>>>(d_w3, wd3);
    cb_prep<<<256, TPB, 0, stream>>>(cb, chb, clb, cn2);

    // ---- E1: 3->64 k3 s1 p1 (direct) ----
    conv_e1<<<2048, TPB, 0, stream>>>(x, e_w1, e_b1, h1, N);
    bn_stats_p<64><<<512, TPB, 0, stream>>>(h1, part, 524288);
    bn_reduce2<64><<<128, 64, 0, stream>>>(part, stats + 0 * 512, 512);
    bn_apply_v<64><<<4096, TPB, 0, stream>>>(h1, stats + 0 * 512, e_g1, e_be1, 524288);

    // ---- E2: 64->128 k4 s2 p1 (MFMA BK=64, fused stats) ----
    conv_mfma<64, 128, 64, 64, 4, 2, 1, 128, 0, 1>
        <<<1024, TPB, 0, stream>>>(h1, we2, e_b2, h2, nullptr, part, zpage, N);
    bn_reduce2<128><<<256, 64, 0, stream>>>(part, stats + 1 * 512, 1024);
    bn_apply_v<128><<<2048, TPB, 0, stream>>>(h2, stats + 1 * 512, e_g2, e_be2, 131072);

    // ---- E3: 128->192 k4 s2 p1 (MFMA BK=64, fused stats, XCD-aware) ----
    conv_mfma<128, 192, 32, 32, 4, 2, 1, 96, 0, 2>
        <<<512, TPB, 0, stream>>>(h2, we3, e_b3, h3, nullptr, part, zpage, N);
    bn_reduce2<192><<<384, 64, 0, stream>>>(part, stats + 2 * 512, 256);
    bn_apply_v<192><<<1024, TPB, 0, stream>>>(h3, stats + 2 * 512, e_g3, e_be3, 32768);

    // ---- E4: 192->256 1x1 (MFMA BK=64, hi/lo split out for VQ) ----
    conv_mfma<192, 256, 16, 16, 1, 1, 0, 128, 2, 2>
        <<<512, TPB, 0, stream>>>(h3, we4, e_b4, zh, zl, nullptr, zpage, N);

    // ---- VQ: fused GEMM+argmin -> gather(with combine) -> loss ----
    vq_gemm<<<512, TPB, 0, stream>>>(zh, zl, chb, clb, cn2, valp, idxp);
    vq_gather2<<<8192, TPB, 0, stream>>>(zh, zl, cb, valp, idxp, hq, rowloss);
    loss_reduce1<<<64, TPB, 0, stream>>>(rowloss, part64);
    loss_finalize<<<1, 64, 0, stream>>>(part64, losses);

    // ---- D1: 256->192 1x1 convT (MFMA BK=64, fused stats, XCD-aware) ----
    conv_mfma<256, 192, 16, 16, 1, 1, 0, 96, 0, 2>
        <<<512, TPB, 0, stream>>>(hq, wd1, d_b1, g1, nullptr, part, zpage, N);
    bn_reduce2<192><<<384, 64, 0, stream>>>(part, stats + 3 * 512, 256);
    bn_apply_v<192><<<1024, TPB, 0, stream>>>(g1, stats + 3 * 512, d_g1, d_be1, 32768);

    // ---- D2: 192->128 convT (NHWC in, CLASS-MAJOR out, linear epilogue) ----
    convt_mfma<192, 128, 16, 16, 128, 0>
        <<<1024, TPB, 0, stream>>>(g1, wd2, d_b2, g2, part, zpage, N);
    bn_reduce2<128><<<256, 64, 0, stream>>>(part, stats + 4 * 512, 1024);
    bn_apply_v<128><<<2048, TPB, 0, stream>>>(g2, stats + 4 * 512, d_g2, d_be2, 131072);

    // ---- D3: 128->64 convT (CLASS-MAJOR in+out, linear epilogue) ----
    convt_mfma<128, 64, 32, 32, 64, 1>
        <<<4096, TPB, 0, stream>>>(g2, wd3, d_b3, g3, part, zpage, N);
    bn_reduce2<64><<<128, 64, 0, stream>>>(part, stats + 5 * 512, 4096);
    bn_apply_v<64><<<4096, TPB, 0, stream>>>(g3, stats + 5 * 512, d_g3, d_be3, 524288);

    // ---- D4: 64->3 k3 s1 p1 (direct, class-major input) -> NCHW fp32 ----
    conv_d4<<<2048, TPB, 0, stream>>>(g3, d_w4, d_b4, out, N);
}

// Round 13
// 752.588 us; speedup vs baseline: 1.0514x; 1.0514x over previous
//
#include <hip/hip_runtime.h>

#define TPB 256

typedef __attribute__((ext_vector_type(4))) float v4f;
typedef __attribute__((ext_vector_type(8))) short v8s;

__device__ __forceinline__ float us2f(unsigned int u) {
    union { unsigned int i; float f; } w; w.i = u << 16; return w.f;
}
__device__ __forceinline__ unsigned short f2us(float f) {
    union { float ff; unsigned int i; } w; w.ff = f;
    unsigned int u = w.i;
    return (unsigned short)((u + 0x7fffu + ((u >> 16) & 1u)) >> 16);
}
// Async global->LDS DMA, 16 B per lane. LDS dest = wave-uniform base + lane*16.
__device__ __forceinline__ void gl_lds16(const unsigned short* g, unsigned short* l) {
    __builtin_amdgcn_global_load_lds(
        (const __attribute__((address_space(1))) unsigned int*)g,
        (__attribute__((address_space(3))) unsigned int*)l, 16, 0, 0);
}

// ---------------------------------------------------------------------------
// Weight repacks (fp32 -> bf16, GEMM-friendly [tap][co][ci])
// ---------------------------------------------------------------------------
template<int CIN, int COUT, int KK>
__global__ __launch_bounds__(TPB) void repack_w(
    const float* __restrict__ w, unsigned short* __restrict__ o)
{
    int idx = blockIdx.x * TPB + threadIdx.x;
    if (idx >= KK * COUT * CIN) return;
    int ci = idx % CIN;
    int co = (idx / CIN) % COUT;
    int kk = idx / (CIN * COUT);
    o[idx] = f2us(w[((size_t)co * CIN + ci) * KK + kk]);
}
template<int CIN, int COUT>
__global__ __launch_bounds__(TPB) void repack_wt1(
    const float* __restrict__ w, unsigned short* __restrict__ o)
{
    int idx = blockIdx.x * TPB + threadIdx.x;
    if (idx >= CIN * COUT) return;
    int ci = idx % CIN;
    int co = idx / CIN;
    o[idx] = f2us(w[(size_t)ci * COUT + co]);
}
template<int CIN, int COUT>
__global__ __launch_bounds__(TPB) void repack_wct(
    const float* __restrict__ w, unsigned short* __restrict__ o)
{
    int idx = blockIdx.x * TPB + threadIdx.x;
    if (idx >= 16 * COUT * CIN) return;
    int ci = idx % CIN;
    int co = (idx / CIN) % COUT;
    int kidx = (idx / (CIN * COUT)) & 3;
    int cls = idx / (CIN * COUT * 4);
    int ohp = cls >> 1, owp = cls & 1;
    int kh = ((ohp + 1) & 1) + 2 * (kidx >> 1);
    int kw = ((owp + 1) & 1) + 2 * (kidx & 1);
    o[idx] = f2us(w[((size_t)ci * COUT + co) * 16 + kh * 4 + kw]);
}

// ---------------------------------------------------------------------------
// Encoder L1: direct conv 3->64, k3 s1 p1, NCHW fp32 x -> NHWC bf16.
// ---------------------------------------------------------------------------
__global__ __launch_bounds__(TPB) void conv_e1(
    const float* __restrict__ x, const float* __restrict__ w,
    const float* __restrict__ bias, unsigned short* __restrict__ y, int N)
{
    __shared__ float wl[27][64];
    int t = threadIdx.x;
    for (int i = t; i < 27 * 64; i += TPB) {
        int co = i & 63;
        int tap = i >> 6;
        int ci = tap / 9, kk = tap % 9;
        wl[tap][co] = w[((size_t)co * 3 + ci) * 9 + kk];
    }
    __syncthreads();
    int p = blockIdx.x * TPB + t;
    int n = p >> 12, oh = (p >> 6) & 63, ow = p & 63;
    float acc[64];
#pragma unroll
    for (int co = 0; co < 64; co++) acc[co] = bias[co];
    for (int ci = 0; ci < 3; ci++) {
#pragma unroll
        for (int kh = 0; kh < 3; kh++) {
            int ih = oh - 1 + kh;
            if ((unsigned)ih >= 64u) continue;
#pragma unroll
            for (int kw = 0; kw < 3; kw++) {
                int iw = ow - 1 + kw;
                if ((unsigned)iw >= 64u) continue;
                float xv = x[(((size_t)n * 3 + ci) * 64 + ih) * 64 + iw];
                int tap = ci * 9 + kh * 3 + kw;
#pragma unroll
                for (int co = 0; co < 64; co++) acc[co] += xv * wl[tap][co];
            }
        }
    }
    unsigned int* yp = (unsigned int*)(y + (size_t)p * 64);
#pragma unroll
    for (int co = 0; co < 64; co += 2)
        yp[co >> 1] = (unsigned int)f2us(acc[co]) | ((unsigned int)f2us(acc[co + 1]) << 16);
}

// ---------------------------------------------------------------------------
// MFMA implicit-GEMM conv, DMA-staged, BK=64, fused BN-stat partials.
// NYB==2: XCD-aware decode (b, b+8 share an XCD under round-robin dispatch).
// OUTM: 0 = bf16 out + BN partials; 2 = split hi/lo bf16 out (no BN).
// ---------------------------------------------------------------------------
template<int CIN, int COUT, int HIN, int WIN, int K, int S, int P, int BN,
         int OUTM, int NYB>
__global__ __launch_bounds__(TPB) void conv_mfma(
    const unsigned short* __restrict__ xin, const unsigned short* __restrict__ wrep,
    const float* __restrict__ bias, void* __restrict__ yout, void* __restrict__ yout2,
    float* __restrict__ part, const unsigned short* __restrict__ zpage, int N)
{
    constexpr int HOUT = (HIN + 2 * P - K) / S + 1;
    constexpr int WOUT = (WIN + 2 * P - K) / S + 1;
    constexpr int RN = BN / 32;
    constexpr int BSEG = BN / 16;
    __shared__ __align__(16) unsigned short Ab[16 * 512];
    __shared__ __align__(16) unsigned short Bb[2 * BSEG * 512];

    const int t = threadIdx.x, lane = t & 63, wave = t >> 6;
    const int wm = wave >> 1, wn = wave & 1;
    int m0, co0;
    if (NYB == 2) {
        int g = (int)blockIdx.x >> 3, xs = (int)blockIdx.x & 7;
        co0 = (g & 1) * BN;
        m0 = (((g >> 1) << 3) + xs) * 128;
    } else {
        m0 = (int)blockIdx.x * 128;
        co0 = 0;
    }
    const int lr = lane & 15, lc = lane >> 4;

    int n_[2], oh_[2], ow_[2];
#pragma unroll
    for (int i = 0; i < 2; i++) {
        int r = m0 + (wave + 4 * i) * 16 + lr;
        n_[i] = r / (HOUT * WOUT);
        int rem = r % (HOUT * WOUT);
        oh_[i] = rem / WOUT;
        ow_[i] = rem % WOUT;
    }

    v4f acc[4][RN];
#pragma unroll
    for (int i = 0; i < 4; i++)
#pragma unroll
        for (int j = 0; j < RN; j++)
#pragma unroll
            for (int r = 0; r < 4; r++) acc[i][j][r] = 0.f;

    for (int kk = 0; kk < K * K; kk++) {
        const int kh = kk / K, kw = kk % K;
        const unsigned short* ga[2];
#pragma unroll
        for (int i = 0; i < 2; i++) {
            int ih = oh_[i] * S - P + kh;
            int iw = ow_[i] * S - P + kw;
            bool av = (unsigned)ih < (unsigned)HIN && (unsigned)iw < (unsigned)WIN;
            ga[i] = av ? xin + (((size_t)n_[i] * HIN + ih) * WIN + iw) * CIN + lc * 8
                       : (const unsigned short*)nullptr;
        }
        const unsigned short* wt = wrep + (size_t)kk * COUT * CIN;
        for (int ci0 = 0; ci0 < CIN; ci0 += 64) {
            __syncthreads();
#pragma unroll
            for (int i = 0; i < 2; i++) {
                const unsigned short* b0 = ga[i] ? ga[i] + ci0 : zpage;
                const unsigned short* b1 = ga[i] ? ga[i] + ci0 + 32 : zpage;
                gl_lds16(b0, &Ab[(wave + 4 * i) * 512]);
                gl_lds16(b1, &Ab[(8 + wave + 4 * i) * 512]);
            }
#pragma unroll
            for (int i = 0; i < 2; i++) {
                int sgb = wave + 4 * i;
                if (sgb < BSEG) {
                    const unsigned short* wb =
                        wt + (size_t)(co0 + sgb * 16 + lr) * CIN + ci0 + lc * 8;
                    gl_lds16(wb, &Bb[sgb * 512]);
                    gl_lds16(wb + 32, &Bb[(BSEG + sgb) * 512]);
                }
            }
            __syncthreads();

#pragma unroll
            for (int kc = 0; kc < 2; kc++) {
                v8s a[4], b[RN];
#pragma unroll
                for (int i = 0; i < 4; i++)
                    a[i] = *(const v8s*)&Ab[(kc * 8 + wm * 4 + i) * 512 + lane * 8];
#pragma unroll
                for (int j = 0; j < RN; j++)
                    b[j] = *(const v8s*)&Bb[(kc * BSEG + wn * RN + j) * 512 + lane * 8];
#pragma unroll
                for (int i = 0; i < 4; i++)
#pragma unroll
                    for (int j = 0; j < RN; j++)
                        acc[i][j] = __builtin_amdgcn_mfma_f32_16x16x32_bf16(a[i], b[j], acc[i][j], 0, 0, 0);
            }
        }
    }

    float sloc[RN], qloc[RN];
#pragma unroll
    for (int j = 0; j < RN; j++) { sloc[j] = 0.f; qloc[j] = 0.f; }

#pragma unroll
    for (int i = 0; i < 4; i++) {
        int mr = wm * 64 + i * 16 + (lane >> 4) * 4;
#pragma unroll
        for (int j = 0; j < RN; j++) {
            int col = co0 + wn * (BN / 2) + j * 16 + (lane & 15);
            float bs = bias[col];
#pragma unroll
            for (int r = 0; r < 4; r++) {
                size_t g = (size_t)(m0 + mr + r) * COUT + col;
                float v = acc[i][j][r] + bs;
                if (OUTM == 2) {
                    unsigned short h = f2us(v);
                    ((unsigned short*)yout)[g] = h;
                    ((unsigned short*)yout2)[g] = f2us(v - us2f(h));
                } else {
                    ((unsigned short*)yout)[g] = f2us(v);
                    sloc[j] += v;
                    qloc[j] += v * v;
                }
            }
        }
    }

    if (OUTM == 0) {
        __syncthreads();
        float* red = (float*)Ab;
        for (int i = t; i < 2 * BN; i += TPB) red[i] = 0.f;
        __syncthreads();
#pragma unroll
        for (int j = 0; j < RN; j++) {
            float s = sloc[j], qv = qloc[j];
            s += __shfl_xor(s, 16); s += __shfl_xor(s, 32);
            qv += __shfl_xor(qv, 16); qv += __shfl_xor(qv, 32);
            if ((lane >> 4) == 0) {
                int cl = wn * (BN / 2) + j * 16 + (lane & 15);
                atomicAdd(&red[cl], s);
                atomicAdd(&red[BN + cl], qv);
            }
        }
        __syncthreads();
        int pb = (NYB == 2) ? (m0 >> 7) : (int)blockIdx.x;
        int PB = (NYB == 2) ? ((int)gridDim.x >> 1) : (int)gridDim.x;
        for (int i = t; i < BN; i += TPB) {
            int col = co0 + i;
            part[(size_t)col * PB + pb] = red[i];
            part[(size_t)(COUT + col) * PB + pb] = red[BN + i];
        }
    }
}

// ---------------------------------------------------------------------------
// MFMA implicit-GEMM transposed conv, k4 s2 p1, BK=64, XCD-aware classes.
// OUTPUT IS CLASS-MAJOR: (cls, n, i, j, co) — linear coalesced epilogue.
// IN_CLS: input tensor is itself class-major.
// ---------------------------------------------------------------------------
template<int CIN, int COUT, int HIN, int WIN, int BN, int IN_CLS>
__global__ __launch_bounds__(TPB) void convt_mfma(
    const unsigned short* __restrict__ xin, const unsigned short* __restrict__ wrep,
    const float* __restrict__ bias, unsigned short* __restrict__ yout,
    float* __restrict__ part, const unsigned short* __restrict__ zpage, int N)
{
    constexpr int RN = BN / 32;
    constexpr int BSEG = BN / 16;
    __shared__ __align__(16) unsigned short Ab[16 * 512];
    __shared__ __align__(16) unsigned short Bb[2 * BSEG * 512];

    const int t = threadIdx.x, lane = t & 63, wave = t >> 6;
    const int wm = wave >> 1, wn = wave & 1;
    const int gdec = (int)blockIdx.x >> 3, xs = (int)blockIdx.x & 7;
    const int cls = gdec & 3;
    const int m0 = (((gdec >> 2) << 3) + xs) * 128;
    const int ohp = cls >> 1, owp = cls & 1;
    const int khb = (ohp + 1) & 1, kwb = (owp + 1) & 1;
    const int dh0 = (ohp + 1 - khb) >> 1, dw0 = (owp + 1 - kwb) >> 1;
    const int lr = lane & 15, lc = lane >> 4;

    int n_[2], i_[2], j_[2];
#pragma unroll
    for (int i = 0; i < 2; i++) {
        int r = m0 + (wave + 4 * i) * 16 + lr;
        n_[i] = r / (HIN * WIN);
        int rem = r % (HIN * WIN);
        i_[i] = rem / WIN;
        j_[i] = rem % WIN;
    }

    v4f acc[4][RN];
#pragma unroll
    for (int i = 0; i < 4; i++)
#pragma unroll
        for (int j = 0; j < RN; j++)
#pragma unroll
            for (int r = 0; r < 4; r++) acc[i][j][r] = 0.f;

    for (int kidx = 0; kidx < 4; kidx++) {
        const int dh = dh0 - (kidx >> 1);
        const int dw = dw0 - (kidx & 1);
        const unsigned short* ga[2];
#pragma unroll
        for (int i = 0; i < 2; i++) {
            int ih = i_[i] + dh;
            int iw = j_[i] + dw;
            bool av = (unsigned)ih < (unsigned)HIN && (unsigned)iw < (unsigned)WIN;
            size_t abase;
            if (IN_CLS) {
                int clsi = ((ih & 1) << 1) | (iw & 1);
                abase = ((((size_t)clsi * N + n_[i]) * (HIN / 2) + (ih >> 1)) * (WIN / 2)
                         + (iw >> 1)) * CIN;
            } else {
                abase = (((size_t)n_[i] * HIN + ih) * WIN + iw) * CIN;
            }
            ga[i] = av ? xin + abase + lc * 8 : (const unsigned short*)nullptr;
        }
        const unsigned short* wk = wrep + (size_t)(cls * 4 + kidx) * COUT * CIN;
        for (int ci0 = 0; ci0 < CIN; ci0 += 64) {
            __syncthreads();
#pragma unroll
            for (int i = 0; i < 2; i++) {
                const unsigned short* b0 = ga[i] ? ga[i] + ci0 : zpage;
                const unsigned short* b1 = ga[i] ? ga[i] + ci0 + 32 : zpage;
                gl_lds16(b0, &Ab[(wave + 4 * i) * 512]);
                gl_lds16(b1, &Ab[(8 + wave + 4 * i) * 512]);
            }
#pragma unroll
            for (int i = 0; i < 2; i++) {
                int sgb = wave + 4 * i;
                if (sgb < BSEG) {
                    const unsigned short* wb =
                        wk + (size_t)(sgb * 16 + lr) * CIN + ci0 + lc * 8;
                    gl_lds16(wb, &Bb[sgb * 512]);
                    gl_lds16(wb + 32, &Bb[(BSEG + sgb) * 512]);
                }
            }
            __syncthreads();

#pragma unroll
            for (int kc = 0; kc < 2; kc++) {
                v8s a[4], b[RN];
#pragma unroll
                for (int i = 0; i < 4; i++)
                    a[i] = *(const v8s*)&Ab[(kc * 8 + wm * 4 + i) * 512 + lane * 8];
#pragma unroll
                for (int j = 0; j < RN; j++)
                    b[j] = *(const v8s*)&Bb[(kc * BSEG + wn * RN + j) * 512 + lane * 8];
#pragma unroll
                for (int i = 0; i < 4; i++)
#pragma unroll
                    for (int j = 0; j < RN; j++)
                        acc[i][j] = __builtin_amdgcn_mfma_f32_16x16x32_bf16(a[i], b[j], acc[i][j], 0, 0, 0);
            }
        }
    }

    float sloc[RN], qloc[RN];
#pragma unroll
    for (int j = 0; j < RN; j++) { sloc[j] = 0.f; qloc[j] = 0.f; }

    const size_t clsbase = (size_t)cls * N * HIN * WIN;
#pragma unroll
    for (int i = 0; i < 4; i++) {
        int mr = wm * 64 + i * 16 + (lane >> 4) * 4;
#pragma unroll
        for (int j = 0; j < RN; j++) {
            int col = wn * (BN / 2) + j * 16 + (lane & 15);
            float bs = bias[col];
#pragma unroll
            for (int r = 0; r < 4; r++) {
                size_t gi = (clsbase + m0 + mr + r) * COUT + col;
                float v = acc[i][j][r] + bs;
                yout[gi] = f2us(v);
                sloc[j] += v;
                qloc[j] += v * v;
            }
        }
    }

    __syncthreads();
    float* red = (float*)Ab;
    for (int i = t; i < 2 * BN; i += TPB) red[i] = 0.f;
    __syncthreads();
#pragma unroll
    for (int j = 0; j < RN; j++) {
        float s = sloc[j], qv = qloc[j];
        s += __shfl_xor(s, 16); s += __shfl_xor(s, 32);
        qv += __shfl_xor(qv, 16); qv += __shfl_xor(qv, 32);
        if ((lane >> 4) == 0) {
            int cl = wn * (BN / 2) + j * 16 + (lane & 15);
            atomicAdd(&red[cl], s);
            atomicAdd(&red[BN + cl], qv);
        }
    }
    __syncthreads();
    int pb = (int)blockIdx.x;
    int PB = (int)gridDim.x;
    for (int i = t; i < BN; i += TPB) {
        part[(size_t)i * PB + pb] = red[i];
        part[(size_t)(COUT + i) * PB + pb] = red[BN + i];
    }
}

// ---------------------------------------------------------------------------
// BN stats pass (only for h1 / conv_e1 output), transposed partial store.
// ---------------------------------------------------------------------------
template<int C>
__global__ __launch_bounds__(TPB) void bn_stats_p(
    const unsigned short* __restrict__ x, float* __restrict__ part, int M)
{
    constexpr int GPT = C / 8;
    constexpr int RPB = TPB / GPT;
    constexpr int ACT = RPB * GPT;
    __shared__ float sred[2 * C];
    int t = threadIdx.x;
    for (int i = t; i < 2 * C; i += TPB) sred[i] = 0.f;
    __syncthreads();
    if (t < ACT) {
        int g = t % GPT, rs = t / GPT;
        float s[8], sq[8];
#pragma unroll
        for (int k = 0; k < 8; k++) { s[k] = 0.f; sq[k] = 0.f; }
        for (int row = blockIdx.x * RPB + rs; row < M; row += gridDim.x * RPB) {
            int4 v = *(const int4*)(x + (size_t)row * C + g * 8);
            const unsigned int* vu = (const unsigned int*)&v;
#pragma unroll
            for (int k = 0; k < 4; k++) {
                float f0 = us2f(vu[k] & 0xffffu);
                float f1 = us2f(vu[k] >> 16);
                s[2 * k] += f0; sq[2 * k] += f0 * f0;
                s[2 * k + 1] += f1; sq[2 * k + 1] += f1 * f1;
            }
        }
        int c0 = g * 8;
#pragma unroll
        for (int k = 0; k < 8; k++) {
            atomicAdd(&sred[c0 + k], s[k]);
            atomicAdd(&sred[C + c0 + k], sq[k]);
        }
    }
    __syncthreads();
    int B = gridDim.x;
    for (int i = t; i < 2 * C; i += TPB)
        part[(size_t)i * B + blockIdx.x] = sred[i];
}

template<int C>
__global__ __launch_bounds__(64) void bn_reduce2(
    const float* __restrict__ part, float* __restrict__ st, int B)
{
    int i = blockIdx.x;
    int lane = threadIdx.x;
    float s = 0.f;
    for (int b = lane; b < B; b += 64) s += part[(size_t)i * B + b];
#pragma unroll
    for (int off = 1; off < 64; off <<= 1) s += __shfl_xor(s, off);
    if (lane == 0) st[i] = s;
}

template<int C>
__global__ __launch_bounds__(TPB) void bn_apply_v(
    unsigned short* __restrict__ x, const float* __restrict__ st,
    const float* __restrict__ g, const float* __restrict__ be, int M)
{
    __shared__ float sc[C], sh[C];
    int t = threadIdx.x;
    float cnt = (float)M;
    for (int c = t; c < C; c += TPB) {
        float m = st[c] / cnt;
        float v = st[C + c] / cnt - m * m;
        float s = g[c] * rsqrtf(v + 1e-5f);
        sc[c] = s;
        sh[c] = be[c] - m * s;
    }
    __syncthreads();
    constexpr int GPT = C / 8;
    size_t tot = (size_t)M * GPT;
    for (size_t slot = (size_t)blockIdx.x * TPB + t; slot < tot;
         slot += (size_t)gridDim.x * TPB) {
        int c0 = (int)(slot % GPT) * 8;
        int4 v = *(int4*)(x + slot * 8);
        unsigned int* vu = (unsigned int*)&v;
#pragma unroll
        for (int k = 0; k < 4; k++) {
            float f0 = fmaxf(us2f(vu[k] & 0xffffu) * sc[c0 + 2 * k] + sh[c0 + 2 * k], 0.f);
            float f1 = fmaxf(us2f(vu[k] >> 16) * sc[c0 + 2 * k + 1] + sh[c0 + 2 * k + 1], 0.f);
            vu[k] = (unsigned int)f2us(f0) | ((unsigned int)f2us(f1) << 16);
        }
        *(int4*)(x + slot * 8) = v;
    }
}

// ---------------------------------------------------------------------------
// VQ stage 1: codebook split hi/lo bf16 + cn2.
// ---------------------------------------------------------------------------
__global__ __launch_bounds__(TPB) void cb_prep(
    const float* __restrict__ cb, unsigned short* __restrict__ chb,
    unsigned short* __restrict__ clb, float* __restrict__ cn2)
{
    int j = blockIdx.x, d = threadIdx.x;
    float v = cb[j * 256 + d];
    unsigned short h = f2us(v);
    chb[j * 256 + d] = h;
    clb[j * 256 + d] = f2us(v - us2f(h));
    float s = v * v;
#pragma unroll
    for (int off = 1; off < 64; off <<= 1) s += __shfl_xor(s, off);
    __shared__ float p[4];
    if ((d & 63) == 0) p[d >> 6] = s;
    __syncthreads();
    if (d == 0) cn2[j] = p[0] + p[1] + p[2] + p[3];
}

// ---------------------------------------------------------------------------
// VQ stage 2: split-bf16 MFMA distance GEMM with fused per-wave argmin.
// Each wave owns 64 cols -> candidate slot row*4 + cbk*2 + wn (race-free).
// ---------------------------------------------------------------------------
__global__ __launch_bounds__(TPB) void vq_gemm(
    const unsigned short* __restrict__ zh, const unsigned short* __restrict__ zl,
    const unsigned short* __restrict__ chb, const unsigned short* __restrict__ clb,
    const float* __restrict__ cn2, float* __restrict__ valp, int* __restrict__ idxp)
{
    __shared__ __align__(16) unsigned short Ah[8 * 512];
    __shared__ __align__(16) unsigned short Al[8 * 512];
    __shared__ __align__(16) unsigned short Bh[8 * 512];
    __shared__ __align__(16) unsigned short Bl[8 * 512];

    const int t = threadIdx.x, lane = t & 63, wave = t >> 6;
    const int wm = wave >> 1, wn = wave & 1;
    const int gdec = (int)blockIdx.x >> 3, xs = (int)blockIdx.x & 7;
    const int cbk = gdec & 1;
    const int m0 = (((gdec >> 1) << 3) + xs) * 128;
    const int co0 = cbk * 128;
    const int lr = lane & 15, lc = lane >> 4;

    size_t a0 = (size_t)(m0 + wave * 16 + lr) * 256 + lc * 8;
    size_t a1 = a0 + 64 * 256;
    size_t b0 = (size_t)(co0 + wave * 16 + lr) * 256 + lc * 8;
    size_t b1 = b0 + 64 * 256;

    v4f acc[4][4];
#pragma unroll
    for (int i = 0; i < 4; i++)
#pragma unroll
        for (int j = 0; j < 4; j++)
#pragma unroll
            for (int r = 0; r < 4; r++) acc[i][j][r] = 0.f;

    for (int ci0 = 0; ci0 < 256; ci0 += 32) {
        __syncthreads();
        gl_lds16(zh + a0 + ci0, &Ah[wave * 512]);
        gl_lds16(zh + a1 + ci0, &Ah[(wave + 4) * 512]);
        gl_lds16(zl + a0 + ci0, &Al[wave * 512]);
        gl_lds16(zl + a1 + ci0, &Al[(wave + 4) * 512]);
        gl_lds16(chb + b0 + ci0, &Bh[wave * 512]);
        gl_lds16(chb + b1 + ci0, &Bh[(wave + 4) * 512]);
        gl_lds16(clb + b0 + ci0, &Bl[wave * 512]);
        gl_lds16(clb + b1 + ci0, &Bl[(wave + 4) * 512]);
        __syncthreads();

        v8s a_h[4], a_l[4], b_h[4], b_l[4];
#pragma unroll
        for (int i = 0; i < 4; i++) {
            a_h[i] = *(const v8s*)&Ah[(wm * 4 + i) * 512 + lane * 8];
            a_l[i] = *(const v8s*)&Al[(wm * 4 + i) * 512 + lane * 8];
        }
#pragma unroll
        for (int j = 0; j < 4; j++) {
            b_h[j] = *(const v8s*)&Bh[(wn * 4 + j) * 512 + lane * 8];
            b_l[j] = *(const v8s*)&Bl[(wn * 4 + j) * 512 + lane * 8];
        }
#pragma unroll
        for (int i = 0; i < 4; i++)
#pragma unroll
            for (int j = 0; j < 4; j++) {
                acc[i][j] = __builtin_amdgcn_mfma_f32_16x16x32_bf16(a_h[i], b_h[j], acc[i][j], 0, 0, 0);
                acc[i][j] = __builtin_amdgcn_mfma_f32_16x16x32_bf16(a_h[i], b_l[j], acc[i][j], 0, 0, 0);
                acc[i][j] = __builtin_amdgcn_mfma_f32_16x16x32_bf16(a_l[i], b_h[j], acc[i][j], 0, 0, 0);
            }
    }

#pragma unroll
    for (int i = 0; i < 4; i++) {
#pragma unroll
        for (int r = 0; r < 4; r++) {
            float best = 3.4e38f;
            int bi = 0;
#pragma unroll
            for (int j = 0; j < 4; j++) {
                int col = co0 + wn * 64 + j * 16 + (lane & 15);
                float d = cn2[col] - 2.f * acc[i][j][r];
                if (d < best || (d == best && col < bi)) { best = d; bi = col; }
            }
#pragma unroll
            for (int off = 1; off < 16; off <<= 1) {
                float ov = __shfl_xor(best, off);
                int oi = __shfl_xor(bi, off);
                if (ov < best || (ov == best && oi < bi)) { best = ov; bi = oi; }
            }
            if ((lane & 15) == 0) {
                int row = m0 + wm * 64 + i * 16 + (lane >> 4) * 4 + r;
                valp[(size_t)row * 4 + cbk * 2 + wn] = best;
                idxp[(size_t)row * 4 + cbk * 2 + wn] = bi;
            }
        }
    }
}

// ---------------------------------------------------------------------------
// VQ stage 3+4 fused: per-row candidate combine + gather + loss.
// ---------------------------------------------------------------------------
__global__ __launch_bounds__(TPB) void vq_gather2(
    const unsigned short* __restrict__ zh, const unsigned short* __restrict__ zl,
    const float* __restrict__ cb, const float* __restrict__ valp,
    const int* __restrict__ idxp, unsigned short* __restrict__ hq,
    float* __restrict__ rowloss)
{
    int row = blockIdx.x * 4 + (threadIdx.x >> 6);
    int lane = threadIdx.x & 63;
    float best = valp[(size_t)row * 4];
    int j = idxp[(size_t)row * 4];
#pragma unroll
    for (int c = 1; c < 4; c++) {
        float v = valp[(size_t)row * 4 + c];
        if (v < best) { best = v; j = idxp[(size_t)row * 4 + c]; }
    }
    ushort4 hv = *(const ushort4*)(zh + (size_t)row * 256 + lane * 4);
    ushort4 lv = *(const ushort4*)(zl + (size_t)row * 256 + lane * 4);
    float4 cv = *(const float4*)(cb + (size_t)j * 256 + lane * 4);
    float z0 = us2f(hv.x) + us2f(lv.x);
    float z1 = us2f(hv.y) + us2f(lv.y);
    float z2 = us2f(hv.z) + us2f(lv.z);
    float z3 = us2f(hv.w) + us2f(lv.w);
    float d0 = z0 - cv.x, d1 = z1 - cv.y, d2 = z2 - cv.z, d3 = z3 - cv.w;
    float d = d0 * d0 + d1 * d1 + d2 * d2 + d3 * d3;
#pragma unroll
    for (int off = 1; off < 64; off <<= 1) d += __shfl_xor(d, off);
    if (lane == 0) rowloss[row] = d;
    ushort4 o;
    o.x = f2us(cv.x); o.y = f2us(cv.y); o.z = f2us(cv.z); o.w = f2us(cv.w);
    *(ushort4*)(hq + (size_t)row * 256 + lane * 4) = o;
}

__global__ __launch_bounds__(TPB) void loss_reduce1(
    const float* __restrict__ rowloss, float* __restrict__ part64)
{
    int t = threadIdx.x;
    int base = blockIdx.x * 512 + t;
    float v = rowloss[base] + rowloss[base + 256];
#pragma unroll
    for (int off = 1; off < 64; off <<= 1) v += __shfl_xor(v, off);
    __shared__ float p[4];
    if ((t & 63) == 0) p[t >> 6] = v;
    __syncthreads();
    if (t == 0) part64[blockIdx.x] = p[0] + p[1] + p[2] + p[3];
}

__global__ __launch_bounds__(64) void loss_finalize(
    const float* __restrict__ part64, float* __restrict__ out2)
{
    float v = part64[threadIdx.x];
    for (int off = 32; off > 0; off >>= 1) v += __shfl_down(v, off);
    if (threadIdx.x == 0) {
        float m = v * (1.0f / 32768.0f);
        out2[0] = m;
        out2[1] = m;
    }
}

// ---------------------------------------------------------------------------
// Decoder L4: LDS-TILED direct conv 64->3, k3 s1 p1. Input g3 is CLASS-MAJOR
// (cls, n, ihh, iwh, co). One block per (n, 16x16 output tile): stage the
// 4-class 10x10-cell halo patch into LDS (zero-filled OOB = conv zero-pad),
// then compute all 9 taps from LDS.
// LDS cell layout [c8 8][cls 4][ihh 10][iwh 10] of 16B: compute-phase lane
// address deltas = {16,4,8}-word offsets -> 2-way bank aliasing only (free).
// ---------------------------------------------------------------------------
__global__ __launch_bounds__(TPB) void conv_d4(
    const unsigned short* __restrict__ xb, const float* __restrict__ w,
    const float* __restrict__ bias, float* __restrict__ out, int N)
{
    __shared__ __align__(16) unsigned short xs[8 * 400 * 8];   // 51.2 KB
    __shared__ float wl[1728];                                  // 6.9 KB
    int4* xsI = (int4*)xs;
    int t = threadIdx.x;
    for (int i = t; i < 1728; i += TPB) {
        int co = i % 3, ci = (i / 3) % 64, tap = i / 192;
        wl[i] = w[((size_t)co * 64 + ci) * 9 + tap];
    }

    const int n = blockIdx.x >> 4;
    const int tile = blockIdx.x & 15;
    const int th = tile >> 2, tw = tile & 3;
    const int ihh0 = 8 * th - 1, iwh0 = 8 * tw - 1;

    // ---- stage patch: 3200 int4 slots (4 cls x 10 ihh x 80 i4) ----
    for (int s = t; s < 3200; s += TPB) {
        int cls = s / 800;
        int rem = s % 800;
        int ihh_l = rem / 80;
        int i4 = rem % 80;
        int iwh_l = i4 >> 3, c8 = i4 & 7;
        int ihh_g = ihh0 + ihh_l;
        int iwh_g = iwh0 + iwh_l;
        int4 v;
        if ((unsigned)ihh_g < 32u && (unsigned)iwh_g < 32u) {
            size_t row = (((size_t)cls * 128 + n) * 32 + ihh_g) * 32 + iwh_g;
            v = *(const int4*)(xb + row * 64 + c8 * 8);
        } else {
            v.x = v.y = v.z = v.w = 0;
        }
        xsI[c8 * 400 + cls * 100 + ihh_l * 10 + iwh_l] = v;
    }
    __syncthreads();

    // ---- compute: one output px per thread ----
    int oh = th * 16 + (t >> 4);
    int ow = tw * 16 + (t & 15);
    float a0 = bias[0], a1 = bias[1], a2 = bias[2];
#pragma unroll
    for (int kh = 0; kh < 3; kh++) {
        int ih = oh - 1 + kh;
#pragma unroll
        for (int kw = 0; kw < 3; kw++) {
            int iw = ow - 1 + kw;
            int clsi = ((ih & 1) << 1) | (iw & 1);
            int base = clsi * 100 + ((ih >> 1) - ihh0) * 10 + ((iw >> 1) - iwh0);
            int tap = kh * 3 + kw;
#pragma unroll
            for (int c8 = 0; c8 < 8; c8++) {
                int4 v = xsI[c8 * 400 + base];
                const unsigned int* vu = (const unsigned int*)&v;
#pragma unroll
                for (int k = 0; k < 4; k++) {
                    unsigned int u = vu[k];
                    float f0 = us2f(u & 0xffffu);
                    float f1 = us2f(u >> 16);
                    const float* wp = &wl[(tap * 64 + c8 * 8 + k * 2) * 3];
                    a0 += f0 * wp[0]; a1 += f0 * wp[1]; a2 += f0 * wp[2];
                    a0 += f1 * wp[3]; a1 += f1 * wp[4]; a2 += f1 * wp[5];
                }
            }
        }
    }
    size_t base = (size_t)n * 3 * 4096 + oh * 64 + ow;
    out[base] = a0;
    out[base + 4096] = a1;
    out[base + 8192] = a2;
}

// ---------------------------------------------------------------------------

extern "C" void kernel_launch(void* const* d_in, const int* in_sizes, int n_in,
                              void* d_out, int out_size, void* d_ws, size_t ws_size,
                              hipStream_t stream) {
    const float* x    = (const float*)d_in[0];
    const float* cb   = (const float*)d_in[1];
    const float* e_w1 = (const float*)d_in[2];  const float* e_b1 = (const float*)d_in[3];
    const float* e_g1 = (const float*)d_in[4];  const float* e_be1 = (const float*)d_in[5];
    const float* e_w2 = (const float*)d_in[6];  const float* e_b2 = (const float*)d_in[7];
    const float* e_g2 = (const float*)d_in[8];  const float* e_be2 = (const float*)d_in[9];
    const float* e_w3 = (const float*)d_in[10]; const float* e_b3 = (const float*)d_in[11];
    const float* e_g3 = (const float*)d_in[12]; const float* e_be3 = (const float*)d_in[13];
    const float* e_w4 = (const float*)d_in[14]; const float* e_b4 = (const float*)d_in[15];
    const float* d_w1 = (const float*)d_in[16]; const float* d_b1 = (const float*)d_in[17];
    const float* d_g1 = (const float*)d_in[18]; const float* d_be1 = (const float*)d_in[19];
    const float* d_w2 = (const float*)d_in[20]; const float* d_b2 = (const float*)d_in[21];
    const float* d_g2 = (const float*)d_in[22]; const float* d_be2 = (const float*)d_in[23];
    const float* d_w3 = (const float*)d_in[24]; const float* d_b3 = (const float*)d_in[25];
    const float* d_g3 = (const float*)d_in[26]; const float* d_be3 = (const float*)d_in[27];
    const float* d_w4 = (const float*)d_in[28]; const float* d_b4 = (const float*)d_in[29];

    float* ws = (float*)d_ws;
    unsigned short* h1 = (unsigned short*)(ws);              // [0, 16777216)
    unsigned short* g3 = h1;                                 // class-major after D3
    unsigned short* h2 = (unsigned short*)(ws + 16777216);   // [.., 25165824)
    unsigned short* g2 = h2;                                 // class-major after D2
    unsigned short* h3 = (unsigned short*)(ws + 25165824);   // [.., 28311552)
    unsigned short* g1 = h3;
    unsigned short* zh = (unsigned short*)(ws + 28311552);   // 8.4M shorts
    unsigned short* zl = (unsigned short*)(ws + 32505856);   // 8.4M shorts
    unsigned short* hq = (unsigned short*)(ws + 36700160);   // [.., 40894464)
    float* stats = ws + 40960000;                            // 3072
    float* cn2 = ws + 40995904;                              // 256
    unsigned short* chb = (unsigned short*)(ws + 40996160);  // 65536 shorts
    unsigned short* clb = (unsigned short*)(ws + 41028928);  // 65536 shorts
    unsigned short* wrep = (unsigned short*)(ws + 41061696);
    unsigned short* we2 = wrep + 0;        // 16*128*64   = 131072
    unsigned short* we3 = wrep + 131072;   // 16*192*128  = 393216
    unsigned short* we4 = wrep + 524288;   // 256*192     = 49152
    unsigned short* wd1 = wrep + 573440;   // 192*256     = 49152
    unsigned short* wd2 = wrep + 622592;   // 4*4*128*192 = 393216
    unsigned short* wd3 = wrep + 1015808;  // 4*4*64*128  = 131072
    float* part = ws + 41635136;           // BN partials / VQ candidates (8.4M floats)
    float* valp = part;                    // 131072 floats (dead outside VQ window)
    int* idxp = (int*)(part + 131072);     // 131072 ints
    float* rowloss = ws + 50023744;                          // 32768
    float* part64 = ws + 50122048;                           // 64
    unsigned short* zpage = (unsigned short*)(ws + 50122112); // 256 B of zeros
    float* out = (float*)d_out;
    float* losses = out + 1572864;

    const int N = 128;

    hipMemsetAsync(zpage, 0, 256, stream);

    // weight / codebook prep (tiny)
    repack_w<64, 128, 16><<<512, TPB, 0, stream>>>(e_w2, we2);
    repack_w<128, 192, 16><<<1536, TPB, 0, stream>>>(e_w3, we3);
    repack_w<192, 256, 1><<<192, TPB, 0, stream>>>(e_w4, we4);
    repack_wt1<256, 192><<<192, TPB, 0, stream>>>(d_w1, wd1);
    repack_wct<192, 128><<<1536, TPB, 0, stream>>>(d_w2, wd2);
    repack_wct<128, 64><<<512, TPB, 0, stream>>>(d_w3, wd3);
    cb_prep<<<256, TPB, 0, stream>>>(cb, chb, clb, cn2);

    // ---- E1: 3->64 k3 s1 p1 (direct) ----
    conv_e1<<<2048, TPB, 0, stream>>>(x, e_w1, e_b1, h1, N);
    bn_stats_p<64><<<512, TPB, 0, stream>>>(h1, part, 524288);
    bn_reduce2<64><<<128, 64, 0, stream>>>(part, stats + 0 * 512, 512);
    bn_apply_v<64><<<4096, TPB, 0, stream>>>(h1, stats + 0 * 512, e_g1, e_be1, 524288);

    // ---- E2: 64->128 k4 s2 p1 (MFMA BK=64, fused stats) ----
    conv_mfma<64, 128, 64, 64, 4, 2, 1, 128, 0, 1>
        <<<1024, TPB, 0, stream>>>(h1, we2, e_b2, h2, nullptr, part, zpage, N);
    bn_reduce2<128><<<256, 64, 0, stream>>>(part, stats + 1 * 512, 1024);
    bn_apply_v<128><<<2048, TPB, 0, stream>>>(h2, stats + 1 * 512, e_g2, e_be2, 131072);

    // ---- E3: 128->192 k4 s2 p1 (MFMA BK=64, fused stats, XCD-aware) ----
    conv_mfma<128, 192, 32, 32, 4, 2, 1, 96, 0, 2>
        <<<512, TPB, 0, stream>>>(h2, we3, e_b3, h3, nullptr, part, zpage, N);
    bn_reduce2<192><<<384, 64, 0, stream>>>(part, stats + 2 * 512, 256);
    bn_apply_v<192><<<1024, TPB, 0, stream>>>(h3, stats + 2 * 512, e_g3, e_be3, 32768);

    // ---- E4: 192->256 1x1 (MFMA BK=64, hi/lo split out for VQ) ----
    conv_mfma<192, 256, 16, 16, 1, 1, 0, 128, 2, 2>
        <<<512, TPB, 0, stream>>>(h3, we4, e_b4, zh, zl, nullptr, zpage, N);

    // ---- VQ: fused GEMM+argmin -> gather(with combine) -> loss ----
    vq_gemm<<<512, TPB, 0, stream>>>(zh, zl, chb, clb, cn2, valp, idxp);
    vq_gather2<<<8192, TPB, 0, stream>>>(zh, zl, cb, valp, idxp, hq, rowloss);
    loss_reduce1<<<64, TPB, 0, stream>>>(rowloss, part64);
    loss_finalize<<<1, 64, 0, stream>>>(part64, losses);

    // ---- D1: 256->192 1x1 convT (MFMA BK=64, fused stats, XCD-aware) ----
    conv_mfma<256, 192, 16, 16, 1, 1, 0, 96, 0, 2>
        <<<512, TPB, 0, stream>>>(hq, wd1, d_b1, g1, nullptr, part, zpage, N);
    bn_reduce2<192><<<384, 64, 0, stream>>>(part, stats + 3 * 512, 256);
    bn_apply_v<192><<<1024, TPB, 0, stream>>>(g1, stats + 3 * 512, d_g1, d_be1, 32768);

    // ---- D2: 192->128 convT (NHWC in, CLASS-MAJOR out, linear epilogue) ----
    convt_mfma<192, 128, 16, 16, 128, 0>
        <<<1024, TPB, 0, stream>>>(g1, wd2, d_b2, g2, part, zpage, N);
    bn_reduce2<128><<<256, 64, 0, stream>>>(part, stats + 4 * 512, 1024);
    bn_apply_v<128><<<2048, TPB, 0, stream>>>(g2, stats + 4 * 512, d_g2, d_be2, 131072);

    // ---- D3: 128->64 convT (CLASS-MAJOR in+out, linear epilogue) ----
    convt_mfma<128, 64, 32, 32, 64, 1>
        <<<4096, TPB, 0, stream>>>(g2, wd3, d_b3, g3, part, zpage, N);
    bn_reduce2<64><<<128, 64, 0, stream>>>(part, stats + 5 * 512, 4096);
    bn_apply_v<64><<<4096, TPB, 0, stream>>>(g3, stats + 5 * 512, d_g3, d_be3, 524288);

    // ---- D4: 64->3 k3 s1 p1 (LDS-tiled, class-major input) -> NCHW fp32 ----
    conv_d4<<<2048, TPB, 0, stream>>>(g3, d_w4, d_b4, out, N);
}

// Round 14
// 739.409 us; speedup vs baseline: 1.0702x; 1.0178x over previous
//
#include <hip/hip_runtime.h>

#define TPB 256

typedef __attribute__((ext_vector_type(4))) float v4f;
typedef __attribute__((ext_vector_type(8))) short v8s;

__device__ __forceinline__ float us2f(unsigned int u) {
    union { unsigned int i; float f; } w; w.i = u << 16; return w.f;
}
__device__ __forceinline__ unsigned short f2us(float f) {
    union { float ff; unsigned int i; } w; w.ff = f;
    unsigned int u = w.i;
    return (unsigned short)((u + 0x7fffu + ((u >> 16) & 1u)) >> 16);
}
// Async global->LDS DMA, 16 B per lane. LDS dest = wave-uniform base + lane*16.
__device__ __forceinline__ void gl_lds16(const unsigned short* g, unsigned short* l) {
    __builtin_amdgcn_global_load_lds(
        (const __attribute__((address_space(1))) unsigned int*)g,
        (__attribute__((address_space(3))) unsigned int*)l, 16, 0, 0);
}

// ---------------------------------------------------------------------------
// Weight repacks (fp32 -> bf16, GEMM-friendly [tap][co][ci])
// ---------------------------------------------------------------------------
template<int CIN, int COUT, int KK>
__global__ __launch_bounds__(TPB) void repack_w(
    const float* __restrict__ w, unsigned short* __restrict__ o)
{
    int idx = blockIdx.x * TPB + threadIdx.x;
    if (idx >= KK * COUT * CIN) return;
    int ci = idx % CIN;
    int co = (idx / CIN) % COUT;
    int kk = idx / (CIN * COUT);
    o[idx] = f2us(w[((size_t)co * CIN + ci) * KK + kk]);
}
template<int CIN, int COUT>
__global__ __launch_bounds__(TPB) void repack_wt1(
    const float* __restrict__ w, unsigned short* __restrict__ o)
{
    int idx = blockIdx.x * TPB + threadIdx.x;
    if (idx >= CIN * COUT) return;
    int ci = idx % CIN;
    int co = idx / CIN;
    o[idx] = f2us(w[(size_t)ci * COUT + co]);
}
template<int CIN, int COUT>
__global__ __launch_bounds__(TPB) void repack_wct(
    const float* __restrict__ w, unsigned short* __restrict__ o)
{
    int idx = blockIdx.x * TPB + threadIdx.x;
    if (idx >= 16 * COUT * CIN) return;
    int ci = idx % CIN;
    int co = (idx / CIN) % COUT;
    int kidx = (idx / (CIN * COUT)) & 3;
    int cls = idx / (CIN * COUT * 4);
    int ohp = cls >> 1, owp = cls & 1;
    int kh = ((ohp + 1) & 1) + 2 * (kidx >> 1);
    int kw = ((owp + 1) & 1) + 2 * (kidx & 1);
    o[idx] = f2us(w[((size_t)ci * COUT + co) * 16 + kh * 4 + kw]);
}

// ---------------------------------------------------------------------------
// Encoder L1: direct conv 3->64, k3 s1 p1, NCHW fp32 x -> NHWC bf16.
// ---------------------------------------------------------------------------
__global__ __launch_bounds__(TPB) void conv_e1(
    const float* __restrict__ x, const float* __restrict__ w,
    const float* __restrict__ bias, unsigned short* __restrict__ y, int N)
{
    __shared__ float wl[27][64];
    int t = threadIdx.x;
    for (int i = t; i < 27 * 64; i += TPB) {
        int co = i & 63;
        int tap = i >> 6;
        int ci = tap / 9, kk = tap % 9;
        wl[tap][co] = w[((size_t)co * 3 + ci) * 9 + kk];
    }
    __syncthreads();
    int p = blockIdx.x * TPB + t;
    int n = p >> 12, oh = (p >> 6) & 63, ow = p & 63;
    float acc[64];
#pragma unroll
    for (int co = 0; co < 64; co++) acc[co] = bias[co];
    for (int ci = 0; ci < 3; ci++) {
#pragma unroll
        for (int kh = 0; kh < 3; kh++) {
            int ih = oh - 1 + kh;
            if ((unsigned)ih >= 64u) continue;
#pragma unroll
            for (int kw = 0; kw < 3; kw++) {
                int iw = ow - 1 + kw;
                if ((unsigned)iw >= 64u) continue;
                float xv = x[(((size_t)n * 3 + ci) * 64 + ih) * 64 + iw];
                int tap = ci * 9 + kh * 3 + kw;
#pragma unroll
                for (int co = 0; co < 64; co++) acc[co] += xv * wl[tap][co];
            }
        }
    }
    unsigned int* yp = (unsigned int*)(y + (size_t)p * 64);
#pragma unroll
    for (int co = 0; co < 64; co += 2)
        yp[co >> 1] = (unsigned int)f2us(acc[co]) | ((unsigned int)f2us(acc[co + 1]) << 16);
}

// ---------------------------------------------------------------------------
// MFMA implicit-GEMM conv, DMA-staged, BK=64, fused BN-stat partials.
// NYB==2: XCD-aware decode (b, b+8 share an XCD under round-robin dispatch).
// OUTM: 0 = bf16 out + BN partials; 2 = split hi/lo bf16 out (no BN).
// ---------------------------------------------------------------------------
template<int CIN, int COUT, int HIN, int WIN, int K, int S, int P, int BN,
         int OUTM, int NYB>
__global__ __launch_bounds__(TPB) void conv_mfma(
    const unsigned short* __restrict__ xin, const unsigned short* __restrict__ wrep,
    const float* __restrict__ bias, void* __restrict__ yout, void* __restrict__ yout2,
    float* __restrict__ part, const unsigned short* __restrict__ zpage, int N)
{
    constexpr int HOUT = (HIN + 2 * P - K) / S + 1;
    constexpr int WOUT = (WIN + 2 * P - K) / S + 1;
    constexpr int RN = BN / 32;
    constexpr int BSEG = BN / 16;
    __shared__ __align__(16) unsigned short Ab[16 * 512];
    __shared__ __align__(16) unsigned short Bb[2 * BSEG * 512];

    const int t = threadIdx.x, lane = t & 63, wave = t >> 6;
    const int wm = wave >> 1, wn = wave & 1;
    int m0, co0;
    if (NYB == 2) {
        int g = (int)blockIdx.x >> 3, xs = (int)blockIdx.x & 7;
        co0 = (g & 1) * BN;
        m0 = (((g >> 1) << 3) + xs) * 128;
    } else {
        m0 = (int)blockIdx.x * 128;
        co0 = 0;
    }
    const int lr = lane & 15, lc = lane >> 4;

    int n_[2], oh_[2], ow_[2];
#pragma unroll
    for (int i = 0; i < 2; i++) {
        int r = m0 + (wave + 4 * i) * 16 + lr;
        n_[i] = r / (HOUT * WOUT);
        int rem = r % (HOUT * WOUT);
        oh_[i] = rem / WOUT;
        ow_[i] = rem % WOUT;
    }

    v4f acc[4][RN];
#pragma unroll
    for (int i = 0; i < 4; i++)
#pragma unroll
        for (int j = 0; j < RN; j++)
#pragma unroll
            for (int r = 0; r < 4; r++) acc[i][j][r] = 0.f;

    for (int kk = 0; kk < K * K; kk++) {
        const int kh = kk / K, kw = kk % K;
        const unsigned short* ga[2];
#pragma unroll
        for (int i = 0; i < 2; i++) {
            int ih = oh_[i] * S - P + kh;
            int iw = ow_[i] * S - P + kw;
            bool av = (unsigned)ih < (unsigned)HIN && (unsigned)iw < (unsigned)WIN;
            ga[i] = av ? xin + (((size_t)n_[i] * HIN + ih) * WIN + iw) * CIN + lc * 8
                       : (const unsigned short*)nullptr;
        }
        const unsigned short* wt = wrep + (size_t)kk * COUT * CIN;
        for (int ci0 = 0; ci0 < CIN; ci0 += 64) {
            __syncthreads();
#pragma unroll
            for (int i = 0; i < 2; i++) {
                const unsigned short* b0 = ga[i] ? ga[i] + ci0 : zpage;
                const unsigned short* b1 = ga[i] ? ga[i] + ci0 + 32 : zpage;
                gl_lds16(b0, &Ab[(wave + 4 * i) * 512]);
                gl_lds16(b1, &Ab[(8 + wave + 4 * i) * 512]);
            }
#pragma unroll
            for (int i = 0; i < 2; i++) {
                int sgb = wave + 4 * i;
                if (sgb < BSEG) {
                    const unsigned short* wb =
                        wt + (size_t)(co0 + sgb * 16 + lr) * CIN + ci0 + lc * 8;
                    gl_lds16(wb, &Bb[sgb * 512]);
                    gl_lds16(wb + 32, &Bb[(BSEG + sgb) * 512]);
                }
            }
            __syncthreads();

#pragma unroll
            for (int kc = 0; kc < 2; kc++) {
                v8s a[4], b[RN];
#pragma unroll
                for (int i = 0; i < 4; i++)
                    a[i] = *(const v8s*)&Ab[(kc * 8 + wm * 4 + i) * 512 + lane * 8];
#pragma unroll
                for (int j = 0; j < RN; j++)
                    b[j] = *(const v8s*)&Bb[(kc * BSEG + wn * RN + j) * 512 + lane * 8];
#pragma unroll
                for (int i = 0; i < 4; i++)
#pragma unroll
                    for (int j = 0; j < RN; j++)
                        acc[i][j] = __builtin_amdgcn_mfma_f32_16x16x32_bf16(a[i], b[j], acc[i][j], 0, 0, 0);
            }
        }
    }

    float sloc[RN], qloc[RN];
#pragma unroll
    for (int j = 0; j < RN; j++) { sloc[j] = 0.f; qloc[j] = 0.f; }

#pragma unroll
    for (int i = 0; i < 4; i++) {
        int mr = wm * 64 + i * 16 + (lane >> 4) * 4;
#pragma unroll
        for (int j = 0; j < RN; j++) {
            int col = co0 + wn * (BN / 2) + j * 16 + (lane & 15);
            float bs = bias[col];
#pragma unroll
            for (int r = 0; r < 4; r++) {
                size_t g = (size_t)(m0 + mr + r) * COUT + col;
                float v = acc[i][j][r] + bs;
                if (OUTM == 2) {
                    unsigned short h = f2us(v);
                    ((unsigned short*)yout)[g] = h;
                    ((unsigned short*)yout2)[g] = f2us(v - us2f(h));
                } else {
                    ((unsigned short*)yout)[g] = f2us(v);
                    sloc[j] += v;
                    qloc[j] += v * v;
                }
            }
        }
    }

    if (OUTM == 0) {
        __syncthreads();
        float* red = (float*)Ab;
        for (int i = t; i < 2 * BN; i += TPB) red[i] = 0.f;
        __syncthreads();
#pragma unroll
        for (int j = 0; j < RN; j++) {
            float s = sloc[j], qv = qloc[j];
            s += __shfl_xor(s, 16); s += __shfl_xor(s, 32);
            qv += __shfl_xor(qv, 16); qv += __shfl_xor(qv, 32);
            if ((lane >> 4) == 0) {
                int cl = wn * (BN / 2) + j * 16 + (lane & 15);
                atomicAdd(&red[cl], s);
                atomicAdd(&red[BN + cl], qv);
            }
        }
        __syncthreads();
        int pb = (NYB == 2) ? (m0 >> 7) : (int)blockIdx.x;
        int PB = (NYB == 2) ? ((int)gridDim.x >> 1) : (int)gridDim.x;
        for (int i = t; i < BN; i += TPB) {
            int col = co0 + i;
            part[(size_t)col * PB + pb] = red[i];
            part[(size_t)(COUT + col) * PB + pb] = red[BN + i];
        }
    }
}

// ---------------------------------------------------------------------------
// MFMA implicit-GEMM transposed conv, k4 s2 p1. 256-ROW M-TILE: each of the
// 4 waves owns 64 rows x 64 cols (acc[4][4]) -> 32 MFMAs per wave per barrier
// (2x r13), half the barrier-drains per output. NCB=2 splits COUT=128 into
// two 64-col grid blocks (A re-read is L2-resident, cheap). Class-major
// output (linear coalesced epilogue); XCD-aware class grouping.
// ---------------------------------------------------------------------------
template<int CIN, int COUT, int HIN, int WIN, int NCB, int IN_CLS>
__global__ __launch_bounds__(TPB) void convt_mfma(
    const unsigned short* __restrict__ xin, const unsigned short* __restrict__ wrep,
    const float* __restrict__ bias, unsigned short* __restrict__ yout,
    float* __restrict__ part, const unsigned short* __restrict__ zpage, int N)
{
    __shared__ __align__(16) unsigned short Ab[32 * 512];   // 32 KB (2 chunks x 16 segs)
    __shared__ __align__(16) unsigned short Bb[8 * 512];    //  8 KB (2 chunks x 4 segs)

    const int t = threadIdx.x, lane = t & 63, wave = t >> 6;
    int gdec = (int)blockIdx.x >> 3, xs = (int)blockIdx.x & 7;
    int cb = 0;
    if (NCB == 2) { cb = gdec & 1; gdec >>= 1; }
    const int cls = gdec & 3;
    const int tile = ((gdec >> 2) << 3) + xs;
    const int m0 = tile * 256;
    const int co0 = cb * 64;
    const int ohp = cls >> 1, owp = cls & 1;
    const int khb = (ohp + 1) & 1, kwb = (owp + 1) & 1;
    const int dh0 = (ohp + 1 - khb) >> 1, dw0 = (owp + 1 - kwb) >> 1;
    const int lr = lane & 15, lc = lane >> 4;

    // 4 staged A-rows per lane: segments wave*4+q, row = m0 + seg*16 + lr
    int n_[4], i_[4], j_[4];
#pragma unroll
    for (int q = 0; q < 4; q++) {
        int r = m0 + (wave * 4 + q) * 16 + lr;
        n_[q] = r / (HIN * WIN);
        int rem = r % (HIN * WIN);
        i_[q] = rem / WIN;
        j_[q] = rem % WIN;
    }

    v4f acc[4][4];
#pragma unroll
    for (int i = 0; i < 4; i++)
#pragma unroll
        for (int j = 0; j < 4; j++)
#pragma unroll
            for (int r = 0; r < 4; r++) acc[i][j][r] = 0.f;

    for (int kidx = 0; kidx < 4; kidx++) {
        const int dh = dh0 - (kidx >> 1);
        const int dw = dw0 - (kidx & 1);
        const unsigned short* ga[4];
#pragma unroll
        for (int q = 0; q < 4; q++) {
            int ih = i_[q] + dh;
            int iw = j_[q] + dw;
            bool av = (unsigned)ih < (unsigned)HIN && (unsigned)iw < (unsigned)WIN;
            size_t abase;
            if (IN_CLS) {
                int clsi = ((ih & 1) << 1) | (iw & 1);
                abase = ((((size_t)clsi * N + n_[q]) * (HIN / 2) + (ih >> 1)) * (WIN / 2)
                         + (iw >> 1)) * CIN;
            } else {
                abase = (((size_t)n_[q] * HIN + ih) * WIN + iw) * CIN;
            }
            ga[q] = av ? xin + abase + lc * 8 : (const unsigned short*)nullptr;
        }
        const unsigned short* wk = wrep + (size_t)(cls * 4 + kidx) * COUT * CIN;
        for (int ci0 = 0; ci0 < CIN; ci0 += 64) {
            __syncthreads();
#pragma unroll
            for (int q = 0; q < 4; q++) {
                const unsigned short* b0 = ga[q] ? ga[q] + ci0 : zpage;
                const unsigned short* b1 = ga[q] ? ga[q] + ci0 + 32 : zpage;
                gl_lds16(b0, &Ab[(wave * 4 + q) * 512]);
                gl_lds16(b1, &Ab[(16 + wave * 4 + q) * 512]);
            }
            {
                const unsigned short* wb =
                    wk + (size_t)(co0 + wave * 16 + lr) * CIN + ci0 + lc * 8;
                gl_lds16(wb, &Bb[wave * 512]);
                gl_lds16(wb + 32, &Bb[(4 + wave) * 512]);
            }
            __syncthreads();

#pragma unroll
            for (int kc = 0; kc < 2; kc++) {
                v8s a[4], b[4];
#pragma unroll
                for (int i = 0; i < 4; i++)
                    a[i] = *(const v8s*)&Ab[(kc * 16 + wave * 4 + i) * 512 + lane * 8];
#pragma unroll
                for (int j = 0; j < 4; j++)
                    b[j] = *(const v8s*)&Bb[(kc * 4 + j) * 512 + lane * 8];
#pragma unroll
                for (int i = 0; i < 4; i++)
#pragma unroll
                    for (int j = 0; j < 4; j++)
                        acc[i][j] = __builtin_amdgcn_mfma_f32_16x16x32_bf16(a[i], b[j], acc[i][j], 0, 0, 0);
            }
        }
    }

    float sloc[4], qloc[4];
#pragma unroll
    for (int j = 0; j < 4; j++) { sloc[j] = 0.f; qloc[j] = 0.f; }

    const size_t clsbase = (size_t)cls * N * HIN * WIN;
#pragma unroll
    for (int i = 0; i < 4; i++) {
        int mr = wave * 64 + i * 16 + (lane >> 4) * 4;
#pragma unroll
        for (int j = 0; j < 4; j++) {
            int col = co0 + j * 16 + (lane & 15);
            float bs = bias[col];
#pragma unroll
            for (int r = 0; r < 4; r++) {
                size_t gi = (clsbase + m0 + mr + r) * COUT + col;
                float v = acc[i][j][r] + bs;
                yout[gi] = f2us(v);
                sloc[j] += v;
                qloc[j] += v * v;
            }
        }
    }

    __syncthreads();
    float* red = (float*)Ab;
    for (int i = t; i < 128; i += TPB) red[i] = 0.f;
    __syncthreads();
#pragma unroll
    for (int j = 0; j < 4; j++) {
        float s = sloc[j], qv = qloc[j];
        s += __shfl_xor(s, 16); s += __shfl_xor(s, 32);
        qv += __shfl_xor(qv, 16); qv += __shfl_xor(qv, 32);
        if ((lane >> 4) == 0) {
            int cl = j * 16 + (lane & 15);
            atomicAdd(&red[cl], s);
            atomicAdd(&red[64 + cl], qv);
        }
    }
    __syncthreads();
    const int TILES = (N * HIN * WIN) >> 8;   // m-tiles per class
    const int PB = 4 * TILES;
    const int pb = cls * TILES + tile;
    for (int i = t; i < 64; i += TPB) {
        part[(size_t)(co0 + i) * PB + pb] = red[i];
        part[(size_t)(COUT + co0 + i) * PB + pb] = red[64 + i];
    }
}

// ---------------------------------------------------------------------------
// BN stats pass (only for h1 / conv_e1 output), transposed partial store.
// ---------------------------------------------------------------------------
template<int C>
__global__ __launch_bounds__(TPB) void bn_stats_p(
    const unsigned short* __restrict__ x, float* __restrict__ part, int M)
{
    constexpr int GPT = C / 8;
    constexpr int RPB = TPB / GPT;
    constexpr int ACT = RPB * GPT;
    __shared__ float sred[2 * C];
    int t = threadIdx.x;
    for (int i = t; i < 2 * C; i += TPB) sred[i] = 0.f;
    __syncthreads();
    if (t < ACT) {
        int g = t % GPT, rs = t / GPT;
        float s[8], sq[8];
#pragma unroll
        for (int k = 0; k < 8; k++) { s[k] = 0.f; sq[k] = 0.f; }
        for (int row = blockIdx.x * RPB + rs; row < M; row += gridDim.x * RPB) {
            int4 v = *(const int4*)(x + (size_t)row * C + g * 8);
            const unsigned int* vu = (const unsigned int*)&v;
#pragma unroll
            for (int k = 0; k < 4; k++) {
                float f0 = us2f(vu[k] & 0xffffu);
                float f1 = us2f(vu[k] >> 16);
                s[2 * k] += f0; sq[2 * k] += f0 * f0;
                s[2 * k + 1] += f1; sq[2 * k + 1] += f1 * f1;
            }
        }
        int c0 = g * 8;
#pragma unroll
        for (int k = 0; k < 8; k++) {
            atomicAdd(&sred[c0 + k], s[k]);
            atomicAdd(&sred[C + c0 + k], sq[k]);
        }
    }
    __syncthreads();
    int B = gridDim.x;
    for (int i = t; i < 2 * C; i += TPB)
        part[(size_t)i * B + blockIdx.x] = sred[i];
}

template<int C>
__global__ __launch_bounds__(64) void bn_reduce2(
    const float* __restrict__ part, float* __restrict__ st, int B)
{
    int i = blockIdx.x;
    int lane = threadIdx.x;
    float s = 0.f;
    for (int b = lane; b < B; b += 64) s += part[(size_t)i * B + b];
#pragma unroll
    for (int off = 1; off < 64; off <<= 1) s += __shfl_xor(s, off);
    if (lane == 0) st[i] = s;
}

template<int C>
__global__ __launch_bounds__(TPB) void bn_apply_v(
    unsigned short* __restrict__ x, const float* __restrict__ st,
    const float* __restrict__ g, const float* __restrict__ be, int M)
{
    __shared__ float sc[C], sh[C];
    int t = threadIdx.x;
    float cnt = (float)M;
    for (int c = t; c < C; c += TPB) {
        float m = st[c] / cnt;
        float v = st[C + c] / cnt - m * m;
        float s = g[c] * rsqrtf(v + 1e-5f);
        sc[c] = s;
        sh[c] = be[c] - m * s;
    }
    __syncthreads();
    constexpr int GPT = C / 8;
    size_t tot = (size_t)M * GPT;
    for (size_t slot = (size_t)blockIdx.x * TPB + t; slot < tot;
         slot += (size_t)gridDim.x * TPB) {
        int c0 = (int)(slot % GPT) * 8;
        int4 v = *(int4*)(x + slot * 8);
        unsigned int* vu = (unsigned int*)&v;
#pragma unroll
        for (int k = 0; k < 4; k++) {
            float f0 = fmaxf(us2f(vu[k] & 0xffffu) * sc[c0 + 2 * k] + sh[c0 + 2 * k], 0.f);
            float f1 = fmaxf(us2f(vu[k] >> 16) * sc[c0 + 2 * k + 1] + sh[c0 + 2 * k + 1], 0.f);
            vu[k] = (unsigned int)f2us(f0) | ((unsigned int)f2us(f1) << 16);
        }
        *(int4*)(x + slot * 8) = v;
    }
}

// ---------------------------------------------------------------------------
// VQ stage 1: codebook split hi/lo bf16 + cn2.
// ---------------------------------------------------------------------------
__global__ __launch_bounds__(TPB) void cb_prep(
    const float* __restrict__ cb, unsigned short* __restrict__ chb,
    unsigned short* __restrict__ clb, float* __restrict__ cn2)
{
    int j = blockIdx.x, d = threadIdx.x;
    float v = cb[j * 256 + d];
    unsigned short h = f2us(v);
    chb[j * 256 + d] = h;
    clb[j * 256 + d] = f2us(v - us2f(h));
    float s = v * v;
#pragma unroll
    for (int off = 1; off < 64; off <<= 1) s += __shfl_xor(s, off);
    __shared__ float p[4];
    if ((d & 63) == 0) p[d >> 6] = s;
    __syncthreads();
    if (d == 0) cn2[j] = p[0] + p[1] + p[2] + p[3];
}

// ---------------------------------------------------------------------------
// VQ stage 2: split-bf16 MFMA distance GEMM with fused per-wave argmin.
// Each wave owns 64 cols -> candidate slot row*4 + cbk*2 + wn (race-free).
// ---------------------------------------------------------------------------
__global__ __launch_bounds__(TPB) void vq_gemm(
    const unsigned short* __restrict__ zh, const unsigned short* __restrict__ zl,
    const unsigned short* __restrict__ chb, const unsigned short* __restrict__ clb,
    const float* __restrict__ cn2, float* __restrict__ valp, int* __restrict__ idxp)
{
    __shared__ __align__(16) unsigned short Ah[8 * 512];
    __shared__ __align__(16) unsigned short Al[8 * 512];
    __shared__ __align__(16) unsigned short Bh[8 * 512];
    __shared__ __align__(16) unsigned short Bl[8 * 512];

    const int t = threadIdx.x, lane = t & 63, wave = t >> 6;
    const int wm = wave >> 1, wn = wave & 1;
    const int gdec = (int)blockIdx.x >> 3, xs = (int)blockIdx.x & 7;
    const int cbk = gdec & 1;
    const int m0 = (((gdec >> 1) << 3) + xs) * 128;
    const int co0 = cbk * 128;
    const int lr = lane & 15, lc = lane >> 4;

    size_t a0 = (size_t)(m0 + wave * 16 + lr) * 256 + lc * 8;
    size_t a1 = a0 + 64 * 256;
    size_t b0 = (size_t)(co0 + wave * 16 + lr) * 256 + lc * 8;
    size_t b1 = b0 + 64 * 256;

    v4f acc[4][4];
#pragma unroll
    for (int i = 0; i < 4; i++)
#pragma unroll
        for (int j = 0; j < 4; j++)
#pragma unroll
            for (int r = 0; r < 4; r++) acc[i][j][r] = 0.f;

    for (int ci0 = 0; ci0 < 256; ci0 += 32) {
        __syncthreads();
        gl_lds16(zh + a0 + ci0, &Ah[wave * 512]);
        gl_lds16(zh + a1 + ci0, &Ah[(wave + 4) * 512]);
        gl_lds16(zl + a0 + ci0, &Al[wave * 512]);
        gl_lds16(zl + a1 + ci0, &Al[(wave + 4) * 512]);
        gl_lds16(chb + b0 + ci0, &Bh[wave * 512]);
        gl_lds16(chb + b1 + ci0, &Bh[(wave + 4) * 512]);
        gl_lds16(clb + b0 + ci0, &Bl[wave * 512]);
        gl_lds16(clb + b1 + ci0, &Bl[(wave + 4) * 512]);
        __syncthreads();

        v8s a_h[4], a_l[4], b_h[4], b_l[4];
#pragma unroll
        for (int i = 0; i < 4; i++) {
            a_h[i] = *(const v8s*)&Ah[(wm * 4 + i) * 512 + lane * 8];
            a_l[i] = *(const v8s*)&Al[(wm * 4 + i) * 512 + lane * 8];
        }
#pragma unroll
        for (int j = 0; j < 4; j++) {
            b_h[j] = *(const v8s*)&Bh[(wn * 4 + j) * 512 + lane * 8];
            b_l[j] = *(const v8s*)&Bl[(wn * 4 + j) * 512 + lane * 8];
        }
#pragma unroll
        for (int i = 0; i < 4; i++)
#pragma unroll
            for (int j = 0; j < 4; j++) {
                acc[i][j] = __builtin_amdgcn_mfma_f32_16x16x32_bf16(a_h[i], b_h[j], acc[i][j], 0, 0, 0);
                acc[i][j] = __builtin_amdgcn_mfma_f32_16x16x32_bf16(a_h[i], b_l[j], acc[i][j], 0, 0, 0);
                acc[i][j] = __builtin_amdgcn_mfma_f32_16x16x32_bf16(a_l[i], b_h[j], acc[i][j], 0, 0, 0);
            }
    }

#pragma unroll
    for (int i = 0; i < 4; i++) {
#pragma unroll
        for (int r = 0; r < 4; r++) {
            float best = 3.4e38f;
            int bi = 0;
#pragma unroll
            for (int j = 0; j < 4; j++) {
                int col = co0 + wn * 64 + j * 16 + (lane & 15);
                float d = cn2[col] - 2.f * acc[i][j][r];
                if (d < best || (d == best && col < bi)) { best = d; bi = col; }
            }
#pragma unroll
            for (int off = 1; off < 16; off <<= 1) {
                float ov = __shfl_xor(best, off);
                int oi = __shfl_xor(bi, off);
                if (ov < best || (ov == best && oi < bi)) { best = ov; bi = oi; }
            }
            if ((lane & 15) == 0) {
                int row = m0 + wm * 64 + i * 16 + (lane >> 4) * 4 + r;
                valp[(size_t)row * 4 + cbk * 2 + wn] = best;
                idxp[(size_t)row * 4 + cbk * 2 + wn] = bi;
            }
        }
    }
}

// ---------------------------------------------------------------------------
// VQ stage 3+4 fused: per-row candidate combine + gather + loss.
// ---------------------------------------------------------------------------
__global__ __launch_bounds__(TPB) void vq_gather2(
    const unsigned short* __restrict__ zh, const unsigned short* __restrict__ zl,
    const float* __restrict__ cb, const float* __restrict__ valp,
    const int* __restrict__ idxp, unsigned short* __restrict__ hq,
    float* __restrict__ rowloss)
{
    int row = blockIdx.x * 4 + (threadIdx.x >> 6);
    int lane = threadIdx.x & 63;
    float best = valp[(size_t)row * 4];
    int j = idxp[(size_t)row * 4];
#pragma unroll
    for (int c = 1; c < 4; c++) {
        float v = valp[(size_t)row * 4 + c];
        if (v < best) { best = v; j = idxp[(size_t)row * 4 + c]; }
    }
    ushort4 hv = *(const ushort4*)(zh + (size_t)row * 256 + lane * 4);
    ushort4 lv = *(const ushort4*)(zl + (size_t)row * 256 + lane * 4);
    float4 cv = *(const float4*)(cb + (size_t)j * 256 + lane * 4);
    float z0 = us2f(hv.x) + us2f(lv.x);
    float z1 = us2f(hv.y) + us2f(lv.y);
    float z2 = us2f(hv.z) + us2f(lv.z);
    float z3 = us2f(hv.w) + us2f(lv.w);
    float d0 = z0 - cv.x, d1 = z1 - cv.y, d2 = z2 - cv.z, d3 = z3 - cv.w;
    float d = d0 * d0 + d1 * d1 + d2 * d2 + d3 * d3;
#pragma unroll
    for (int off = 1; off < 64; off <<= 1) d += __shfl_xor(d, off);
    if (lane == 0) rowloss[row] = d;
    ushort4 o;
    o.x = f2us(cv.x); o.y = f2us(cv.y); o.z = f2us(cv.z); o.w = f2us(cv.w);
    *(ushort4*)(hq + (size_t)row * 256 + lane * 4) = o;
}

__global__ __launch_bounds__(TPB) void loss_reduce1(
    const float* __restrict__ rowloss, float* __restrict__ part64)
{
    int t = threadIdx.x;
    int base = blockIdx.x * 512 + t;
    float v = rowloss[base] + rowloss[base + 256];
#pragma unroll
    for (int off = 1; off < 64; off <<= 1) v += __shfl_xor(v, off);
    __shared__ float p[4];
    if ((t & 63) == 0) p[t >> 6] = v;
    __syncthreads();
    if (t == 0) part64[blockIdx.x] = p[0] + p[1] + p[2] + p[3];
}

__global__ __launch_bounds__(64) void loss_finalize(
    const float* __restrict__ part64, float* __restrict__ out2)
{
    float v = part64[threadIdx.x];
    for (int off = 32; off > 0; off >>= 1) v += __shfl_down(v, off);
    if (threadIdx.x == 0) {
        float m = v * (1.0f / 32768.0f);
        out2[0] = m;
        out2[1] = m;
    }
}

// ---------------------------------------------------------------------------
// Decoder L4: LDS-TILED direct conv 64->3, k3 s1 p1, class-major input.
// ---------------------------------------------------------------------------
__global__ __launch_bounds__(TPB) void conv_d4(
    const unsigned short* __restrict__ xb, const float* __restrict__ w,
    const float* __restrict__ bias, float* __restrict__ out, int N)
{
    __shared__ __align__(16) unsigned short xs[8 * 400 * 8];   // 51.2 KB
    __shared__ float wl[1728];
    int4* xsI = (int4*)xs;
    int t = threadIdx.x;
    for (int i = t; i < 1728; i += TPB) {
        int co = i % 3, ci = (i / 3) % 64, tap = i / 192;
        wl[i] = w[((size_t)co * 64 + ci) * 9 + tap];
    }

    const int n = blockIdx.x >> 4;
    const int tile = blockIdx.x & 15;
    const int th = tile >> 2, tw = tile & 3;
    const int ihh0 = 8 * th - 1, iwh0 = 8 * tw - 1;

    for (int s = t; s < 3200; s += TPB) {
        int cls = s / 800;
        int rem = s % 800;
        int ihh_l = rem / 80;
        int i4 = rem % 80;
        int iwh_l = i4 >> 3, c8 = i4 & 7;
        int ihh_g = ihh0 + ihh_l;
        int iwh_g = iwh0 + iwh_l;
        int4 v;
        if ((unsigned)ihh_g < 32u && (unsigned)iwh_g < 32u) {
            size_t row = (((size_t)cls * 128 + n) * 32 + ihh_g) * 32 + iwh_g;
            v = *(const int4*)(xb + row * 64 + c8 * 8);
        } else {
            v.x = v.y = v.z = v.w = 0;
        }
        xsI[c8 * 400 + cls * 100 + ihh_l * 10 + iwh_l] = v;
    }
    __syncthreads();

    int oh = th * 16 + (t >> 4);
    int ow = tw * 16 + (t & 15);
    float a0 = bias[0], a1 = bias[1], a2 = bias[2];
#pragma unroll
    for (int kh = 0; kh < 3; kh++) {
        int ih = oh - 1 + kh;
#pragma unroll
        for (int kw = 0; kw < 3; kw++) {
            int iw = ow - 1 + kw;
            int clsi = ((ih & 1) << 1) | (iw & 1);
            int base = clsi * 100 + ((ih >> 1) - ihh0) * 10 + ((iw >> 1) - iwh0);
            int tap = kh * 3 + kw;
#pragma unroll
            for (int c8 = 0; c8 < 8; c8++) {
                int4 v = xsI[c8 * 400 + base];
                const unsigned int* vu = (const unsigned int*)&v;
#pragma unroll
                for (int k = 0; k < 4; k++) {
                    unsigned int u = vu[k];
                    float f0 = us2f(u & 0xffffu);
                    float f1 = us2f(u >> 16);
                    const float* wp = &wl[(tap * 64 + c8 * 8 + k * 2) * 3];
                    a0 += f0 * wp[0]; a1 += f0 * wp[1]; a2 += f0 * wp[2];
                    a0 += f1 * wp[3]; a1 += f1 * wp[4]; a2 += f1 * wp[5];
                }
            }
        }
    }
    size_t base = (size_t)n * 3 * 4096 + oh * 64 + ow;
    out[base] = a0;
    out[base + 4096] = a1;
    out[base + 8192] = a2;
}

// ---------------------------------------------------------------------------

extern "C" void kernel_launch(void* const* d_in, const int* in_sizes, int n_in,
                              void* d_out, int out_size, void* d_ws, size_t ws_size,
                              hipStream_t stream) {
    const float* x    = (const float*)d_in[0];
    const float* cb   = (const float*)d_in[1];
    const float* e_w1 = (const float*)d_in[2];  const float* e_b1 = (const float*)d_in[3];
    const float* e_g1 = (const float*)d_in[4];  const float* e_be1 = (const float*)d_in[5];
    const float* e_w2 = (const float*)d_in[6];  const float* e_b2 = (const float*)d_in[7];
    const float* e_g2 = (const float*)d_in[8];  const float* e_be2 = (const float*)d_in[9];
    const float* e_w3 = (const float*)d_in[10]; const float* e_b3 = (const float*)d_in[11];
    const float* e_g3 = (const float*)d_in[12]; const float* e_be3 = (const float*)d_in[13];
    const float* e_w4 = (const float*)d_in[14]; const float* e_b4 = (const float*)d_in[15];
    const float* d_w1 = (const float*)d_in[16]; const float* d_b1 = (const float*)d_in[17];
    const float* d_g1 = (const float*)d_in[18]; const float* d_be1 = (const float*)d_in[19];
    const float* d_w2 = (const float*)d_in[20]; const float* d_b2 = (const float*)d_in[21];
    const float* d_g2 = (const float*)d_in[22]; const float* d_be2 = (const float*)d_in[23];
    const float* d_w3 = (const float*)d_in[24]; const float* d_b3 = (const float*)d_in[25];
    const float* d_g3 = (const float*)d_in[26]; const float* d_be3 = (const float*)d_in[27];
    const float* d_w4 = (const float*)d_in[28]; const float* d_b4 = (const float*)d_in[29];

    float* ws = (float*)d_ws;
    unsigned short* h1 = (unsigned short*)(ws);              // [0, 16777216)
    unsigned short* g3 = h1;                                 // class-major after D3
    unsigned short* h2 = (unsigned short*)(ws + 16777216);   // [.., 25165824)
    unsigned short* g2 = h2;                                 // class-major after D2
    unsigned short* h3 = (unsigned short*)(ws + 25165824);   // [.., 28311552)
    unsigned short* g1 = h3;
    unsigned short* zh = (unsigned short*)(ws + 28311552);   // 8.4M shorts
    unsigned short* zl = (unsigned short*)(ws + 32505856);   // 8.4M shorts
    unsigned short* hq = (unsigned short*)(ws + 36700160);   // [.., 40894464)
    float* stats = ws + 40960000;                            // 3072
    float* cn2 = ws + 40995904;                              // 256
    unsigned short* chb = (unsigned short*)(ws + 40996160);  // 65536 shorts
    unsigned short* clb = (unsigned short*)(ws + 41028928);  // 65536 shorts
    unsigned short* wrep = (unsigned short*)(ws + 41061696);
    unsigned short* we2 = wrep + 0;        // 16*128*64   = 131072
    unsigned short* we3 = wrep + 131072;   // 16*192*128  = 393216
    unsigned short* we4 = wrep + 524288;   // 256*192     = 49152
    unsigned short* wd1 = wrep + 573440;   // 192*256     = 49152
    unsigned short* wd2 = wrep + 622592;   // 4*4*128*192 = 393216
    unsigned short* wd3 = wrep + 1015808;  // 4*4*64*128  = 131072
    float* part = ws + 41635136;           // BN partials / VQ candidates (8.4M floats)
    float* valp = part;                    // 131072 floats (dead outside VQ window)
    int* idxp = (int*)(part + 131072);     // 131072 ints
    float* rowloss = ws + 50023744;                          // 32768
    float* part64 = ws + 50122048;                           // 64
    unsigned short* zpage = (unsigned short*)(ws + 50122112); // 256 B of zeros
    float* out = (float*)d_out;
    float* losses = out + 1572864;

    const int N = 128;

    hipMemsetAsync(zpage, 0, 256, stream);

    // weight / codebook prep (tiny)
    repack_w<64, 128, 16><<<512, TPB, 0, stream>>>(e_w2, we2);
    repack_w<128, 192, 16><<<1536, TPB, 0, stream>>>(e_w3, we3);
    repack_w<192, 256, 1><<<192, TPB, 0, stream>>>(e_w4, we4);
    repack_wt1<256, 192><<<192, TPB, 0, stream>>>(d_w1, wd1);
    repack_wct<192, 128><<<1536, TPB, 0, stream>>>(d_w2, wd2);
    repack_wct<128, 64><<<512, TPB, 0, stream>>>(d_w3, wd3);
    cb_prep<<<256, TPB, 0, stream>>>(cb, chb, clb, cn2);

    // ---- E1: 3->64 k3 s1 p1 (direct) ----
    conv_e1<<<2048, TPB, 0, stream>>>(x, e_w1, e_b1, h1, N);
    bn_stats_p<64><<<512, TPB, 0, stream>>>(h1, part, 524288);
    bn_reduce2<64><<<128, 64, 0, stream>>>(part, stats + 0 * 512, 512);
    bn_apply_v<64><<<4096, TPB, 0, stream>>>(h1, stats + 0 * 512, e_g1, e_be1, 524288);

    // ---- E2: 64->128 k4 s2 p1 (MFMA BK=64, fused stats) ----
    conv_mfma<64, 128, 64, 64, 4, 2, 1, 128, 0, 1>
        <<<1024, TPB, 0, stream>>>(h1, we2, e_b2, h2, nullptr, part, zpage, N);
    bn_reduce2<128><<<256, 64, 0, stream>>>(part, stats + 1 * 512, 1024);
    bn_apply_v<128><<<2048, TPB, 0, stream>>>(h2, stats + 1 * 512, e_g2, e_be2, 131072);

    // ---- E3: 128->192 k4 s2 p1 (MFMA BK=64, fused stats, XCD-aware) ----
    conv_mfma<128, 192, 32, 32, 4, 2, 1, 96, 0, 2>
        <<<512, TPB, 0, stream>>>(h2, we3, e_b3, h3, nullptr, part, zpage, N);
    bn_reduce2<192><<<384, 64, 0, stream>>>(part, stats + 2 * 512, 256);
    bn_apply_v<192><<<1024, TPB, 0, stream>>>(h3, stats + 2 * 512, e_g3, e_be3, 32768);

    // ---- E4: 192->256 1x1 (MFMA BK=64, hi/lo split out for VQ) ----
    conv_mfma<192, 256, 16, 16, 1, 1, 0, 128, 2, 2>
        <<<512, TPB, 0, stream>>>(h3, we4, e_b4, zh, zl, nullptr, zpage, N);

    // ---- VQ: fused GEMM+argmin -> gather(with combine) -> loss ----
    vq_gemm<<<512, TPB, 0, stream>>>(zh, zl, chb, clb, cn2, valp, idxp);
    vq_gather2<<<8192, TPB, 0, stream>>>(zh, zl, cb, valp, idxp, hq, rowloss);
    loss_reduce1<<<64, TPB, 0, stream>>>(rowloss, part64);
    loss_finalize<<<1, 64, 0, stream>>>(part64, losses);

    // ---- D1: 256->192 1x1 convT (MFMA BK=64, fused stats, XCD-aware) ----
    conv_mfma<256, 192, 16, 16, 1, 1, 0, 96, 0, 2>
        <<<512, TPB, 0, stream>>>(hq, wd1, d_b1, g1, nullptr, part, zpage, N);
    bn_reduce2<192><<<384, 64, 0, stream>>>(part, stats + 3 * 512, 256);
    bn_apply_v<192><<<1024, TPB, 0, stream>>>(g1, stats + 3 * 512, d_g1, d_be1, 32768);

    // ---- D2: 192->128 convT, 256-row tiles, co-split (NHWC in, cls-major out) ----
    convt_mfma<192, 128, 16, 16, 2, 0>
        <<<1024, TPB, 0, stream>>>(g1, wd2, d_b2, g2, part, zpage, N);
    bn_reduce2<128><<<256, 64, 0, stream>>>(part, stats + 4 * 512, 512);
    bn_apply_v<128><<<2048, TPB, 0, stream>>>(g2, stats + 4 * 512, d_g2, d_be2, 131072);

    // ---- D3: 128->64 convT, 256-row tiles (cls-major in+out) ----
    convt_mfma<128, 64, 32, 32, 1, 1>
        <<<2048, TPB, 0, stream>>>(g2, wd3, d_b3, g3, part, zpage, N);
    bn_reduce2<64><<<128, 64, 0, stream>>>(part, stats + 5 * 512, 2048);
    bn_apply_v<64><<<4096, TPB, 0, stream>>>(g3, stats + 5 * 512, d_g3, d_be3, 524288);

    // ---- D4: 64->3 k3 s1 p1 (LDS-tiled, class-major input) -> NCHW fp32 ----
    conv_d4<<<2048, TPB, 0, stream>>>(g3, d_w4, d_b4, out, N);
}